// Round 1
// baseline (2454.039 us; speedup 1.0000x reference)
//
#include <hip/hip_runtime.h>
#include <hip/hip_bf16.h>
#include <math.h>

#define NEG_SLOPE 0.2f

// ---------------- helpers ----------------

__device__ __forceinline__ float atomicMaxFloat(float* addr, float val) {
    // Classic bit-trick: positive floats ordered as ints, negative as reversed uints.
    if (val >= 0.0f) {
        return __int_as_float(atomicMax((int*)addr, __float_as_int(val)));
    } else {
        return __uint_as_float(atomicMin((unsigned int*)addr, __float_as_uint(val)));
    }
}

// ---------------- GEMM: C[M,N] = A[M,K] @ B[K,N] (f32) ----------------
// 64x64 tile, 16x16 threads, 4x4 per thread, K-step 16. K must be mult of 16.
__global__ void gemm_f32(const float* __restrict__ A, const float* __restrict__ B,
                         float* __restrict__ C, int M, int K, int N) {
    __shared__ float As[64][16];
    __shared__ float Bs[16][64];
    int tx = threadIdx.x;          // 0..15
    int ty = threadIdx.y;          // 0..15
    int row0 = blockIdx.y * 64 + ty * 4;
    int col0 = blockIdx.x * 64 + tx * 4;
    float acc[4][4] = {};
    int t = ty * 16 + tx;
    for (int k0 = 0; k0 < K; k0 += 16) {
#pragma unroll
        for (int i = 0; i < 4; ++i) {
            int idx = t + i * 256;
            int r = idx >> 4, c = idx & 15;             // As[r][c]
            int gr = blockIdx.y * 64 + r;
            As[r][c] = (gr < M) ? A[(long)gr * K + k0 + c] : 0.0f;
            int r2 = idx >> 6, c2 = idx & 63;           // Bs[r2][c2]
            int gc = blockIdx.x * 64 + c2;
            Bs[r2][c2] = (gc < N) ? B[(long)(k0 + r2) * N + gc] : 0.0f;
        }
        __syncthreads();
#pragma unroll
        for (int kk = 0; kk < 16; ++kk) {
            float a[4], b[4];
#pragma unroll
            for (int i = 0; i < 4; ++i) a[i] = As[ty * 4 + i][kk];
#pragma unroll
            for (int j = 0; j < 4; ++j) b[j] = Bs[kk][tx * 4 + j];
#pragma unroll
            for (int i = 0; i < 4; ++i)
#pragma unroll
                for (int j = 0; j < 4; ++j) acc[i][j] += a[i] * b[j];
        }
        __syncthreads();
    }
#pragma unroll
    for (int i = 0; i < 4; ++i) {
        int r = row0 + i;
        if (r >= M) continue;
#pragma unroll
        for (int j = 0; j < 4; ++j) {
            int c = col0 + j;
            if (c < N) C[(long)r * N + c] = acc[i][j];
        }
    }
}

// ---------------- alpha_src / alpha_dst per (node, head) ----------------
__global__ void alpha_kernel(const float* __restrict__ H, const float* __restrict__ a_src,
                             const float* __restrict__ a_dst, float* __restrict__ as_,
                             float* __restrict__ ad_, int Nn, int Hh, int C) {
    int i = blockIdx.x * blockDim.x + threadIdx.x;
    if (i >= Nn * Hh) return;
    int n = i / Hh, h = i % Hh;
    const float* hp = H + ((long)n * Hh + h) * C;
    const float* asv = a_src + h * C;
    const float* adv = a_dst + h * C;
    float s = 0.f, d = 0.f;
    for (int c = 0; c < C; ++c) {
        float v = hp[c];
        s += v * asv[c];
        d += v * adv[c];
    }
    as_[i] = s;
    ad_[i] = d;
}

// ---------------- init segment buffers + zero out ----------------
__global__ void init_seg(float* __restrict__ m, float* __restrict__ dn,
                         float* __restrict__ out, int NH, int NHC) {
    int t = blockIdx.x * blockDim.x + threadIdx.x;
    if (t < NH) { m[t] = -__builtin_inff(); dn[t] = 0.0f; }
    if (t < NHC) out[t] = 0.0f;
}

// ---------------- edge pass 1: e = leaky_relu(as[src]+ad[dst]); segment max ----------------
__global__ void edge_max(const int* __restrict__ src, const int* __restrict__ dst,
                         const float* __restrict__ as_, const float* __restrict__ ad_,
                         float* __restrict__ ebuf, float* __restrict__ m,
                         int E, int Etot, int Hh) {
    int t = blockIdx.x * blockDim.x + threadIdx.x;
    if (t >= Etot * Hh) return;
    int e = t / Hh, h = t - e * Hh;
    int s = (e < E) ? src[e] : (e - E);
    int d = (e < E) ? dst[e] : (e - E);
    float v = as_[s * Hh + h] + ad_[d * Hh + h];
    v = (v > 0.0f) ? v : NEG_SLOPE * v;
    ebuf[t] = v;
    atomicMaxFloat(&m[d * Hh + h], v);
}

// ---------------- edge pass 2: ex = exp(e - m[dst]); segment sum ----------------
__global__ void edge_exp(const int* __restrict__ src, const int* __restrict__ dst,
                         float* __restrict__ ebuf, const float* __restrict__ m,
                         float* __restrict__ dn, int E, int Etot, int Hh) {
    int t = blockIdx.x * blockDim.x + threadIdx.x;
    if (t >= Etot * Hh) return;
    int e = t / Hh, h = t - e * Hh;
    int d = (e < E) ? dst[e] : (e - E);
    float ex = expf(ebuf[t] - m[d * Hh + h]);
    ebuf[t] = ex;
    atomicAdd(&dn[d * Hh + h], ex);
}

// ---------------- edge pass 3: out[dst] += h[src] * alpha  (wave per edge) ----------------
__global__ void edge_scatter(const int* __restrict__ src, const int* __restrict__ dst,
                             const float* __restrict__ H, const float* __restrict__ ebuf,
                             const float* __restrict__ dn, float* __restrict__ out,
                             int E, int Etot, int Hh, int C) {
    int wave = (blockIdx.x * blockDim.x + threadIdx.x) >> 6;
    int lane = threadIdx.x & 63;
    if (wave >= Etot) return;
    int e = wave;
    int s = (e < E) ? src[e] : (e - E);
    int d = (e < E) ? dst[e] : (e - E);
    int HC = Hh * C;
    const float* hs = H + (long)s * HC;
    float* od = out + (long)d * HC;
    for (int c = lane; c < HC; c += 64) {
        int h = c / C;
        float alpha = ebuf[e * Hh + h] / (dn[d * Hh + h] + 1e-16f);
        atomicAdd(&od[c], hs[c] * alpha);
    }
}

// ---------------- bias + activation (0=none, 1=relu, 2=tanh) ----------------
__global__ void bias_act(float* __restrict__ out, const float* __restrict__ bias,
                         int Nn, int HC, int act) {
    int t = blockIdx.x * blockDim.x + threadIdx.x;
    if (t >= Nn * HC) return;
    int c = t % HC;
    float v = out[t] + bias[c];
    if (act == 1) v = fmaxf(v, 0.0f);
    else if (act == 2) v = tanhf(v);
    out[t] = v;
}

// ---------------- launch ----------------

extern "C" void kernel_launch(void* const* d_in, const int* in_sizes, int n_in,
                              void* d_out, int out_size, void* d_ws, size_t ws_size,
                              hipStream_t stream) {
    const float* x    = (const float*)d_in[0];
    const int*   ei   = (const int*)d_in[1];
    const float* W1   = (const float*)d_in[2];
    const float* a1s  = (const float*)d_in[3];
    const float* a1d  = (const float*)d_in[4];
    const float* b1   = (const float*)d_in[5];
    const float* W2   = (const float*)d_in[6];
    const float* a2s  = (const float*)d_in[7];
    const float* a2d  = (const float*)d_in[8];
    const float* b2   = (const float*)d_in[9];
    const float* W3   = (const float*)d_in[10];
    const float* a3s  = (const float*)d_in[11];
    const float* a3d  = (const float*)d_in[12];
    const float* b3   = (const float*)d_in[13];
    const float* Wc   = (const float*)d_in[14];
    const float* bc   = (const float*)d_in[15];

    const int F0 = 256;
    int N = in_sizes[0] / F0;          // 50000
    int E = in_sizes[1] / 2;           // 800000
    int Etot = E + N;                  // + self loops
    const int* srcI = ei;
    const int* dstI = ei + E;

    // workspace layout (floats)
    float* ws = (float*)d_ws;
    float* bufA = ws;                   // N*384 (H buffer, max HC)
    float* bufB = bufA + (long)N * 384; // N*384 (layer1 out / layer3 out)
    float* bufC = bufB + (long)N * 384; // N*128 (layer2 out)
    float* ebuf = bufC + (long)N * 128; // Etot*4 (max heads)
    float* as_  = ebuf + (long)Etot * 4;
    float* ad_  = as_ + (long)N * 4;
    float* m_   = ad_ + (long)N * 4;
    float* dn_  = m_ + (long)N * 4;

    auto run_gat = [&](const float* X, int Fin, const float* W, const float* av_s,
                       const float* av_d, const float* bias, int Hh, int C,
                       float* Hbuf, float* Obuf, int act) {
        int HC = Hh * C;
        // H = X @ W
        dim3 gg((HC + 63) / 64, (N + 63) / 64), gb(16, 16);
        gemm_f32<<<gg, gb, 0, stream>>>(X, W, Hbuf, N, Fin, HC);
        // alpha_src/dst
        int nh = N * Hh;
        alpha_kernel<<<(nh + 255) / 256, 256, 0, stream>>>(Hbuf, av_s, av_d, as_, ad_, N, Hh, C);
        // init m/denom/out
        int nhc = N * HC;
        int mx = nhc > nh ? nhc : nh;
        init_seg<<<(mx + 255) / 256, 256, 0, stream>>>(m_, dn_, Obuf, nh, nhc);
        // edge passes
        int eh = Etot * Hh;
        edge_max<<<(eh + 255) / 256, 256, 0, stream>>>(srcI, dstI, as_, ad_, ebuf, m_, E, Etot, Hh);
        edge_exp<<<(eh + 255) / 256, 256, 0, stream>>>(srcI, dstI, ebuf, m_, dn_, E, Etot, Hh);
        long sthreads = (long)Etot * 64;
        edge_scatter<<<(int)((sthreads + 255) / 256), 256, 0, stream>>>(
            srcI, dstI, Hbuf, ebuf, dn_, Obuf, E, Etot, Hh, C);
        // bias + activation
        bias_act<<<(nhc + 255) / 256, 256, 0, stream>>>(Obuf, bias, N, HC, act);
    };

    // Layer 1: 256 -> 4x96, relu
    run_gat(x, 256, W1, a1s, a1d, b1, 4, 96, bufA, bufB, 1);
    // Layer 2: 384 -> 1x128, tanh
    run_gat(bufB, 384, W2, a2s, a2d, b2, 1, 128, bufA, bufC, 2);
    // Layer 3: 128 -> 1x64, tanh
    run_gat(bufC, 128, W3, a3s, a3d, b3, 1, 64, bufA, bufB, 2);

    // Classifier: out = bufB @ Wc + bc   [N,40]
    float* out = (float*)d_out;
    dim3 gg((40 + 63) / 64, (N + 63) / 64), gb(16, 16);
    gemm_f32<<<gg, gb, 0, stream>>>(bufB, Wc, out, N, 64, 40);
    bias_act<<<(N * 40 + 255) / 256, 256, 0, stream>>>(out, bc, N, 40, 0);
}

// Round 2
// 1418.499 us; speedup vs baseline: 1.7300x; 1.7300x over previous
//
#include <hip/hip_runtime.h>
#include <hip/hip_bf16.h>
#include <math.h>

#define NEG_SLOPE 0.2f

// ---------------- helpers ----------------

__device__ __forceinline__ float atomicMaxFloat(float* addr, float val) {
    if (val >= 0.0f) {
        return __int_as_float(atomicMax((int*)addr, __float_as_int(val)));
    } else {
        return __uint_as_float(atomicMin((unsigned int*)addr, __float_as_uint(val)));
    }
}

// ---------------- GEMM: C[M,N] = A[M,K] @ B[K,N] (f32) ----------------
__global__ void gemm_f32(const float* __restrict__ A, const float* __restrict__ B,
                         float* __restrict__ C, int M, int K, int N) {
    __shared__ float As[64][16];
    __shared__ float Bs[16][64];
    int tx = threadIdx.x;          // 0..15
    int ty = threadIdx.y;          // 0..15
    int row0 = blockIdx.y * 64 + ty * 4;
    int col0 = blockIdx.x * 64 + tx * 4;
    float acc[4][4] = {};
    int t = ty * 16 + tx;
    for (int k0 = 0; k0 < K; k0 += 16) {
#pragma unroll
        for (int i = 0; i < 4; ++i) {
            int idx = t + i * 256;
            int r = idx >> 4, c = idx & 15;
            int gr = blockIdx.y * 64 + r;
            As[r][c] = (gr < M) ? A[(long)gr * K + k0 + c] : 0.0f;
            int r2 = idx >> 6, c2 = idx & 63;
            int gc = blockIdx.x * 64 + c2;
            Bs[r2][c2] = (gc < N) ? B[(long)(k0 + r2) * N + gc] : 0.0f;
        }
        __syncthreads();
#pragma unroll
        for (int kk = 0; kk < 16; ++kk) {
            float a[4], b[4];
#pragma unroll
            for (int i = 0; i < 4; ++i) a[i] = As[ty * 4 + i][kk];
#pragma unroll
            for (int j = 0; j < 4; ++j) b[j] = Bs[kk][tx * 4 + j];
#pragma unroll
            for (int i = 0; i < 4; ++i)
#pragma unroll
                for (int j = 0; j < 4; ++j) acc[i][j] += a[i] * b[j];
        }
        __syncthreads();
    }
#pragma unroll
    for (int i = 0; i < 4; ++i) {
        int r = row0 + i;
        if (r >= M) continue;
#pragma unroll
        for (int j = 0; j < 4; ++j) {
            int c = col0 + j;
            if (c < N) C[(long)r * N + c] = acc[i][j];
        }
    }
}

// ---------------- CSR build ----------------

__global__ void hist_kernel(const int* __restrict__ dst, int* __restrict__ cnt,
                            int E, int Etot) {
    int e = blockIdx.x * blockDim.x + threadIdx.x;
    if (e >= Etot) return;
    int d = (e < E) ? dst[e] : (e - E);
    atomicAdd(&cnt[d], 1);
}

__global__ void zero_int(int* __restrict__ p, int n) {
    int t = blockIdx.x * blockDim.x + threadIdx.x;
    if (t < n) p[t] = 0;
}

// per-block exclusive scan of cnt -> rowptr partials; block totals -> bsum
__global__ void scan1(const int* __restrict__ cnt, int* __restrict__ rowptr,
                      int* __restrict__ bsum, int n) {
    __shared__ int s[256];
    int i = blockIdx.x * 256 + threadIdx.x;
    int v = (i < n) ? cnt[i] : 0;
    s[threadIdx.x] = v;
    __syncthreads();
    for (int off = 1; off < 256; off <<= 1) {
        int t = (threadIdx.x >= off) ? s[threadIdx.x - off] : 0;
        __syncthreads();
        s[threadIdx.x] += t;
        __syncthreads();
    }
    if (i < n) rowptr[i] = s[threadIdx.x] - v;   // exclusive partial
    if (threadIdx.x == 255) bsum[blockIdx.x] = s[255];
}

// single-block exclusive scan of bsum (nb <= 256)
__global__ void scan2(int* __restrict__ bsum, int nb) {
    __shared__ int s[256];
    int v = (threadIdx.x < nb) ? bsum[threadIdx.x] : 0;
    s[threadIdx.x] = v;
    __syncthreads();
    for (int off = 1; off < 256; off <<= 1) {
        int t = (threadIdx.x >= off) ? s[threadIdx.x - off] : 0;
        __syncthreads();
        s[threadIdx.x] += t;
        __syncthreads();
    }
    if (threadIdx.x < nb) bsum[threadIdx.x] = s[threadIdx.x] - v;
}

// add block offsets; zero cnt for reuse as cursor; write rowptr[n]=Etot
__global__ void scan3(int* __restrict__ rowptr, const int* __restrict__ bsum,
                      int* __restrict__ cnt, int n, int Etot) {
    int i = blockIdx.x * 256 + threadIdx.x;
    if (i < n) {
        rowptr[i] += bsum[blockIdx.x];
        cnt[i] = 0;
    }
    if (i == 0) rowptr[n] = Etot;
}

__global__ void fill_kernel(const int* __restrict__ src, const int* __restrict__ dst,
                            const int* __restrict__ rowptr, int* __restrict__ cursor,
                            int* __restrict__ esrc, int* __restrict__ edst,
                            int E, int Etot) {
    int e = blockIdx.x * blockDim.x + threadIdx.x;
    if (e >= Etot) return;
    int s = (e < E) ? src[e] : (e - E);
    int d = (e < E) ? dst[e] : (e - E);
    int pos = atomicAdd(&cursor[d], 1);
    int slot = rowptr[d] + pos;
    esrc[slot] = s;
    edst[slot] = d;
}

// ---------------- alpha_src / alpha_dst per (node, head) ----------------
__global__ void alpha_kernel(const float* __restrict__ H, const float* __restrict__ a_src,
                             const float* __restrict__ a_dst, float* __restrict__ as_,
                             float* __restrict__ ad_, int Nn, int Hh, int C) {
    int i = blockIdx.x * blockDim.x + threadIdx.x;
    if (i >= Nn * Hh) return;
    int n = i / Hh, h = i % Hh;
    const float* hp = H + ((long)n * Hh + h) * C;
    const float* asv = a_src + h * C;
    const float* adv = a_dst + h * C;
    float s = 0.f, d = 0.f;
    for (int c = 0; c < C; ++c) {
        float v = hp[c];
        s += v * asv[c];
        d += v * adv[c];
    }
    as_[i] = s;
    ad_[i] = d;
}

// ---------------- init segment buffers ----------------
__global__ void init_seg(float* __restrict__ m, float* __restrict__ dn, int NH) {
    int t = blockIdx.x * blockDim.x + threadIdx.x;
    if (t < NH) { m[t] = -__builtin_inff(); dn[t] = 0.0f; }
}

// ---------------- edge pass 1 (slot order): leaky logits + segment max ----------------
__global__ void edge_max(const int* __restrict__ esrc, const int* __restrict__ edst,
                         const float* __restrict__ as_, const float* __restrict__ ad_,
                         float* __restrict__ ebuf, float* __restrict__ m,
                         int Etot, int Hh) {
    int t = blockIdx.x * blockDim.x + threadIdx.x;
    if (t >= Etot * Hh) return;
    int e = t / Hh, h = t - e * Hh;
    int s = esrc[e], d = edst[e];
    float v = as_[s * Hh + h] + ad_[d * Hh + h];
    v = (v > 0.0f) ? v : NEG_SLOPE * v;
    ebuf[t] = v;
    atomicMaxFloat(&m[d * Hh + h], v);
}

// ---------------- edge pass 2: ex = exp(e - m[dst]); segment sum ----------------
__global__ void edge_exp(const int* __restrict__ edst, float* __restrict__ ebuf,
                         const float* __restrict__ m, float* __restrict__ dn,
                         int Etot, int Hh) {
    int t = blockIdx.x * blockDim.x + threadIdx.x;
    if (t >= Etot * Hh) return;
    int e = t / Hh, h = t - e * Hh;
    int d = edst[e];
    float ex = expf(ebuf[t] - m[d * Hh + h]);
    ebuf[t] = ex;
    atomicAdd(&dn[d * Hh + h], ex);
}

// ---------------- node gather: out[d] = sum_e alpha_e * h[src_e]  + bias, act ----------
// one block (128 threads) per destination node
__global__ void node_gather(const int* __restrict__ rowptr, const int* __restrict__ esrc,
                            const float* __restrict__ H, const float* __restrict__ ebuf,
                            const float* __restrict__ dn, const float* __restrict__ bias,
                            float* __restrict__ out, int Hh, int C, int act) {
    int d = blockIdx.x;
    int begin = rowptr[d], end = rowptr[d + 1];
    int HC = Hh * C;
    __shared__ int sSrc[64];
    __shared__ float sAl[64 * 4];
    __shared__ float sDn[4];
    if (threadIdx.x < Hh) sDn[threadIdx.x] = dn[d * Hh + threadIdx.x] + 1e-16f;

    float acc[3] = {0.f, 0.f, 0.f};
    int c0 = threadIdx.x;
    int h0 = c0 / C, h1 = (c0 + 128) / C, h2 = (c0 + 256) / C;

    for (int chunk = begin; chunk < end; chunk += 64) {
        int n = end - chunk; if (n > 64) n = 64;
        __syncthreads();
        if (threadIdx.x < n) sSrc[threadIdx.x] = esrc[chunk + threadIdx.x];
        for (int t = threadIdx.x; t < n * Hh; t += blockDim.x) {
            int k = t / Hh, h = t - k * Hh;
            sAl[t] = ebuf[(long)(chunk + k) * Hh + h] / sDn[h];
        }
        __syncthreads();
        for (int k = 0; k < n; ++k) {
            int s = sSrc[k];
            const float* hp = H + (long)s * HC;
            float a0 = sAl[k * Hh + h0];
            acc[0] += hp[c0] * a0;
            if (HC > 128) acc[1] += hp[c0 + 128] * sAl[k * Hh + h1];
            if (HC > 256) acc[2] += hp[c0 + 256] * sAl[k * Hh + h2];
        }
    }
#pragma unroll
    for (int ci = 0; ci < 3; ++ci) {
        int c = c0 + ci * 128;
        if (c >= HC) break;
        float v = acc[ci] + bias[c];
        if (act == 1) v = fmaxf(v, 0.0f);
        else if (act == 2) v = tanhf(v);
        out[(long)d * HC + c] = v;
    }
}

// ---------------- bias (classifier) ----------------
__global__ void bias_add(float* __restrict__ out, const float* __restrict__ bias,
                         int Nn, int HC) {
    int t = blockIdx.x * blockDim.x + threadIdx.x;
    if (t >= Nn * HC) return;
    out[t] += bias[t % HC];
}

// ---------------- launch ----------------

extern "C" void kernel_launch(void* const* d_in, const int* in_sizes, int n_in,
                              void* d_out, int out_size, void* d_ws, size_t ws_size,
                              hipStream_t stream) {
    const float* x    = (const float*)d_in[0];
    const int*   ei   = (const int*)d_in[1];
    const float* W1   = (const float*)d_in[2];
    const float* a1s  = (const float*)d_in[3];
    const float* a1d  = (const float*)d_in[4];
    const float* b1   = (const float*)d_in[5];
    const float* W2   = (const float*)d_in[6];
    const float* a2s  = (const float*)d_in[7];
    const float* a2d  = (const float*)d_in[8];
    const float* b2   = (const float*)d_in[9];
    const float* W3   = (const float*)d_in[10];
    const float* a3s  = (const float*)d_in[11];
    const float* a3d  = (const float*)d_in[12];
    const float* b3   = (const float*)d_in[13];
    const float* Wc   = (const float*)d_in[14];
    const float* bc   = (const float*)d_in[15];

    const int F0 = 256;
    int N = in_sizes[0] / F0;          // 50000
    int E = in_sizes[1] / 2;           // 800000
    int Etot = E + N;
    const int* srcI = ei;
    const int* dstI = ei + E;

    // workspace layout
    float* ws = (float*)d_ws;
    float* bufA = ws;                   // N*384
    float* bufB = bufA + (long)N * 384; // N*384
    float* bufC = bufB + (long)N * 384; // N*128
    float* ebuf = bufC + (long)N * 128; // Etot*4
    float* as_  = ebuf + (long)Etot * 4;
    float* ad_  = as_ + (long)N * 4;
    float* m_   = ad_ + (long)N * 4;
    float* dn_  = m_ + (long)N * 4;
    int*   rowptr = (int*)(dn_ + (long)N * 4);   // N+1
    int*   cnt    = rowptr + (N + 1);            // N
    int*   esrc   = cnt + N;                     // Etot
    int*   edst   = esrc + Etot;                 // Etot
    int*   bsum   = edst + Etot;                 // 256

    int nb = (N + 255) / 256;  // 196 blocks <= 256

    // ---- CSR build (graph is layer-invariant; build once) ----
    zero_int<<<(N + 255) / 256, 256, 0, stream>>>(cnt, N);
    hist_kernel<<<(Etot + 255) / 256, 256, 0, stream>>>(dstI, cnt, E, Etot);
    scan1<<<nb, 256, 0, stream>>>(cnt, rowptr, bsum, N);
    scan2<<<1, 256, 0, stream>>>(bsum, nb);
    scan3<<<nb, 256, 0, stream>>>(rowptr, bsum, cnt, N, Etot);
    fill_kernel<<<(Etot + 255) / 256, 256, 0, stream>>>(srcI, dstI, rowptr, cnt,
                                                        esrc, edst, E, Etot);

    auto run_gat = [&](const float* X, int Fin, const float* W, const float* av_s,
                       const float* av_d, const float* bias, int Hh, int C,
                       float* Hbuf, float* Obuf, int act) {
        int HC = Hh * C;
        dim3 gg((HC + 63) / 64, (N + 63) / 64), gb(16, 16);
        gemm_f32<<<gg, gb, 0, stream>>>(X, W, Hbuf, N, Fin, HC);
        int nh = N * Hh;
        alpha_kernel<<<(nh + 255) / 256, 256, 0, stream>>>(Hbuf, av_s, av_d, as_, ad_, N, Hh, C);
        init_seg<<<(nh + 255) / 256, 256, 0, stream>>>(m_, dn_, nh);
        int eh = Etot * Hh;
        edge_max<<<(eh + 255) / 256, 256, 0, stream>>>(esrc, edst, as_, ad_, ebuf, m_, Etot, Hh);
        edge_exp<<<(eh + 255) / 256, 256, 0, stream>>>(edst, ebuf, m_, dn_, Etot, Hh);
        node_gather<<<N, 128, 0, stream>>>(rowptr, esrc, Hbuf, ebuf, dn_, bias, Obuf, Hh, C, act);
    };

    // Layer 1: 256 -> 4x96, relu
    run_gat(x, 256, W1, a1s, a1d, b1, 4, 96, bufA, bufB, 1);
    // Layer 2: 384 -> 1x128, tanh
    run_gat(bufB, 384, W2, a2s, a2d, b2, 1, 128, bufA, bufC, 2);
    // Layer 3: 128 -> 1x64, tanh
    run_gat(bufC, 128, W3, a3s, a3d, b3, 1, 64, bufA, bufB, 2);

    // Classifier: out = bufB @ Wc + bc   [N,40]
    float* out = (float*)d_out;
    dim3 gg((40 + 63) / 64, (N + 63) / 64), gb(16, 16);
    gemm_f32<<<gg, gb, 0, stream>>>(bufB, Wc, out, N, 64, 40);
    bias_add<<<(N * 40 + 255) / 256, 256, 0, stream>>>(out, bc, N, 40);
}

// Round 3
// 795.244 us; speedup vs baseline: 3.0859x; 1.7837x over previous
//
#include <hip/hip_runtime.h>
#include <hip/hip_bf16.h>
#include <math.h>

#define NEG_SLOPE 0.2f

typedef __attribute__((ext_vector_type(8))) short short8v;   // 8 bf16
typedef __attribute__((ext_vector_type(4))) float f32x4;

// ---------------- helpers ----------------

__device__ __forceinline__ float atomicMaxFloat(float* addr, float val) {
    if (val >= 0.0f) {
        return __int_as_float(atomicMax((int*)addr, __float_as_int(val)));
    } else {
        return __uint_as_float(atomicMin((unsigned int*)addr, __float_as_uint(val)));
    }
}

// ---------------- casts / weight prep ----------------

// f32 -> bf16, 4 elems/thread (n must be divisible by 4)
__global__ void cast_bf16_4(const float* __restrict__ in, __hip_bfloat16* __restrict__ out,
                            long n) {
    long i = ((long)blockIdx.x * blockDim.x + threadIdx.x) * 4;
    if (i >= n) return;
    float4 v = *(const float4*)(in + i);
    __hip_bfloat162* o = (__hip_bfloat162*)(out + i);
    o[0] = __hip_bfloat162{__float2bfloat16(v.x), __float2bfloat16(v.y)};
    o[1] = __hip_bfloat162{__float2bfloat16(v.z), __float2bfloat16(v.w)};
}

// W [K][N] f32 -> WT [N][K] bf16
__global__ void wtrans(const float* __restrict__ W, __hip_bfloat16* __restrict__ WT,
                       int K, int N) {
    int t = blockIdx.x * blockDim.x + threadIdx.x;
    if (t >= K * N) return;
    int n = t / K, k = t - n * K;
    WT[t] = __float2bfloat16(W[(long)k * N + n]);
}

// ---------------- MFMA bf16 GEMM: C[M,N] = A[M,K] @ BT[N,K]^T ----------------
// 64x64 tile, 256 threads (4 waves as 2x2), K-step 32. K % 32 == 0.
// Writes bf16 (Cb) or f32 (Cf, with optional bias).
__global__ __launch_bounds__(256) void gemm_bf16(
        const __hip_bfloat16* __restrict__ A, const __hip_bfloat16* __restrict__ BT,
        __hip_bfloat16* __restrict__ Cb, float* __restrict__ Cf,
        const float* __restrict__ bias, int M, int K, int N) {
    __shared__ __align__(16) __hip_bfloat16 As[64][40];  // +8 pad -> 2-way (free)
    __shared__ __align__(16) __hip_bfloat16 Bs[64][40];
    int t = threadIdx.x;
    int wave = t >> 6, lane = t & 63;
    int wm = wave >> 1, wn = wave & 1;
    int m0 = blockIdx.y * 64, n0 = blockIdx.x * 64;
    int lrow = lane & 15, kb = lane >> 4;

    f32x4 acc[2][2] = {};
    int srow = t >> 2, scol = (t & 3) * 8;

    for (int k0 = 0; k0 < K; k0 += 32) {
        int gr = m0 + srow;
        short8v av = {};
        if (gr < M) av = *(const short8v*)(A + (long)gr * K + k0 + scol);
        int gn = n0 + srow;
        short8v bv = {};
        if (gn < N) bv = *(const short8v*)(BT + (long)gn * K + k0 + scol);
        __syncthreads();
        *(short8v*)&As[srow][scol] = av;
        *(short8v*)&Bs[srow][scol] = bv;
        __syncthreads();
        short8v a0 = *(const short8v*)&As[wm * 32 + lrow][kb * 8];
        short8v a1 = *(const short8v*)&As[wm * 32 + 16 + lrow][kb * 8];
        short8v b0 = *(const short8v*)&Bs[wn * 32 + lrow][kb * 8];
        short8v b1 = *(const short8v*)&Bs[wn * 32 + 16 + lrow][kb * 8];
        acc[0][0] = __builtin_amdgcn_mfma_f32_16x16x32_bf16(a0, b0, acc[0][0], 0, 0, 0);
        acc[0][1] = __builtin_amdgcn_mfma_f32_16x16x32_bf16(a0, b1, acc[0][1], 0, 0, 0);
        acc[1][0] = __builtin_amdgcn_mfma_f32_16x16x32_bf16(a1, b0, acc[1][0], 0, 0, 0);
        acc[1][1] = __builtin_amdgcn_mfma_f32_16x16x32_bf16(a1, b1, acc[1][1], 0, 0, 0);
    }
#pragma unroll
    for (int i = 0; i < 2; ++i)
#pragma unroll
        for (int j = 0; j < 2; ++j) {
            int col = n0 + wn * 32 + j * 16 + lrow;
            if (col >= N) continue;
#pragma unroll
            for (int r = 0; r < 4; ++r) {
                int row = m0 + wm * 32 + i * 16 + kb * 4 + r;
                if (row >= M) continue;
                float v = acc[i][j][r];
                if (bias) v += bias[col];
                if (Cf) Cf[(long)row * N + col] = v;
                else Cb[(long)row * N + col] = __float2bfloat16(v);
            }
        }
}

// ---------------- CSR build ----------------

__global__ void hist_kernel(const int* __restrict__ dst, int* __restrict__ cnt,
                            int E, int Etot) {
    int e = blockIdx.x * blockDim.x + threadIdx.x;
    if (e >= Etot) return;
    int d = (e < E) ? dst[e] : (e - E);
    atomicAdd(&cnt[d], 1);
}

__global__ void zero_int(int* __restrict__ p, int n) {
    int t = blockIdx.x * blockDim.x + threadIdx.x;
    if (t < n) p[t] = 0;
}

__global__ void scan1(const int* __restrict__ cnt, int* __restrict__ rowptr,
                      int* __restrict__ bsum, int n) {
    __shared__ int s[256];
    int i = blockIdx.x * 256 + threadIdx.x;
    int v = (i < n) ? cnt[i] : 0;
    s[threadIdx.x] = v;
    __syncthreads();
    for (int off = 1; off < 256; off <<= 1) {
        int t = (threadIdx.x >= off) ? s[threadIdx.x - off] : 0;
        __syncthreads();
        s[threadIdx.x] += t;
        __syncthreads();
    }
    if (i < n) rowptr[i] = s[threadIdx.x] - v;
    if (threadIdx.x == 255) bsum[blockIdx.x] = s[255];
}

__global__ void scan2(int* __restrict__ bsum, int nb) {
    __shared__ int s[256];
    int v = (threadIdx.x < nb) ? bsum[threadIdx.x] : 0;
    s[threadIdx.x] = v;
    __syncthreads();
    for (int off = 1; off < 256; off <<= 1) {
        int t = (threadIdx.x >= off) ? s[threadIdx.x - off] : 0;
        __syncthreads();
        s[threadIdx.x] += t;
        __syncthreads();
    }
    if (threadIdx.x < nb) bsum[threadIdx.x] = s[threadIdx.x] - v;
}

__global__ void scan3(int* __restrict__ rowptr, const int* __restrict__ bsum,
                      int* __restrict__ cnt, int n, int Etot) {
    int i = blockIdx.x * 256 + threadIdx.x;
    if (i < n) {
        rowptr[i] += bsum[blockIdx.x];
        cnt[i] = 0;
    }
    if (i == 0) rowptr[n] = Etot;
}

__global__ void fill_kernel(const int* __restrict__ src, const int* __restrict__ dst,
                            const int* __restrict__ rowptr, int* __restrict__ cursor,
                            int* __restrict__ esrc, int* __restrict__ edst,
                            int E, int Etot) {
    int e = blockIdx.x * blockDim.x + threadIdx.x;
    if (e >= Etot) return;
    int s = (e < E) ? src[e] : (e - E);
    int d = (e < E) ? dst[e] : (e - E);
    int pos = atomicAdd(&cursor[d], 1);
    int slot = rowptr[d] + pos;
    esrc[slot] = s;
    edst[slot] = d;
}

// ---------------- alpha_src / alpha_dst per (node, head) ----------------
__global__ void alpha_kernel(const __hip_bfloat16* __restrict__ H,
                             const float* __restrict__ a_src, const float* __restrict__ a_dst,
                             float* __restrict__ as_, float* __restrict__ ad_,
                             int Nn, int Hh, int C) {
    int i = blockIdx.x * blockDim.x + threadIdx.x;
    if (i >= Nn * Hh) return;
    int n = i / Hh, h = i % Hh;
    const __hip_bfloat16* hp = H + ((long)n * Hh + h) * C;
    const float* asv = a_src + h * C;
    const float* adv = a_dst + h * C;
    float s = 0.f, d = 0.f;
    for (int c = 0; c < C; ++c) {
        float v = __bfloat162float(hp[c]);
        s += v * asv[c];
        d += v * adv[c];
    }
    as_[i] = s;
    ad_[i] = d;
}

// ---------------- init segment buffers ----------------
__global__ void init_seg(float* __restrict__ m, float* __restrict__ dn, int NH) {
    int t = blockIdx.x * blockDim.x + threadIdx.x;
    if (t < NH) { m[t] = -__builtin_inff(); dn[t] = 0.0f; }
}

// ---------------- edge pass 1: leaky logits + segment max ----------------
__global__ void edge_max(const int* __restrict__ esrc, const int* __restrict__ edst,
                         const float* __restrict__ as_, const float* __restrict__ ad_,
                         float* __restrict__ ebuf, float* __restrict__ m,
                         int Etot, int Hh) {
    int t = blockIdx.x * blockDim.x + threadIdx.x;
    if (t >= Etot * Hh) return;
    int e = t / Hh, h = t - e * Hh;
    int s = esrc[e], d = edst[e];
    float v = as_[s * Hh + h] + ad_[d * Hh + h];
    v = (v > 0.0f) ? v : NEG_SLOPE * v;
    ebuf[t] = v;
    atomicMaxFloat(&m[d * Hh + h], v);
}

// ---------------- edge pass 2: ex = exp(e - m[dst]); segment sum ----------------
__global__ void edge_exp(const int* __restrict__ edst, float* __restrict__ ebuf,
                         const float* __restrict__ m, float* __restrict__ dn,
                         int Etot, int Hh) {
    int t = blockIdx.x * blockDim.x + threadIdx.x;
    if (t >= Etot * Hh) return;
    int e = t / Hh, h = t - e * Hh;
    int d = edst[e];
    float ex = expf(ebuf[t] - m[d * Hh + h]);
    ebuf[t] = ex;
    atomicAdd(&dn[d * Hh + h], ex);
}

// ---------------- node gather: out[d] = sum_e alpha_e * h[src_e] + bias, act --------
// one block per destination node; pairs: thread handles channels (2t, 2t+1)
__global__ void node_gather(const int* __restrict__ rowptr, const int* __restrict__ esrc,
                            const __hip_bfloat16* __restrict__ H,
                            const float* __restrict__ ebuf, const float* __restrict__ dn,
                            const float* __restrict__ bias, __hip_bfloat16* __restrict__ out,
                            int Hh, int C, int act, int pairs) {
    int d = blockIdx.x;
    int begin = rowptr[d], end = rowptr[d + 1];
    int HC = Hh * C;
    __shared__ int sSrc[64];
    __shared__ float sAl[64 * 4];
    __shared__ float sDn[4];
    if (threadIdx.x < Hh) sDn[threadIdx.x] = dn[d * Hh + threadIdx.x] + 1e-16f;

    float ax = 0.f, ay = 0.f;
    int c0 = pairs ? (threadIdx.x * 2) : threadIdx.x;
    int h = c0 / C;   // pairs never straddle heads (C even)

    for (int chunk = begin; chunk < end; chunk += 64) {
        int n = end - chunk; if (n > 64) n = 64;
        __syncthreads();
        if (threadIdx.x < n) sSrc[threadIdx.x] = esrc[chunk + threadIdx.x];
        for (int t = threadIdx.x; t < n * Hh; t += blockDim.x) {
            int k = t / Hh, hh = t - k * Hh;
            sAl[t] = ebuf[(long)(chunk + k) * Hh + hh] / sDn[hh];
        }
        __syncthreads();
        if (pairs) {
            for (int k = 0; k < n; ++k) {
                int s = sSrc[k];
                float a = sAl[k * Hh + h];
                __hip_bfloat162 v = *(const __hip_bfloat162*)(H + (long)s * HC + c0);
                ax += a * __bfloat162float(v.x);
                ay += a * __bfloat162float(v.y);
            }
        } else {
            for (int k = 0; k < n; ++k) {
                int s = sSrc[k];
                float a = sAl[k * Hh + h];
                ax += a * __bfloat162float(H[(long)s * HC + c0]);
            }
        }
    }
    float vx = ax + bias[c0];
    if (act == 1) vx = fmaxf(vx, 0.0f);
    else if (act == 2) vx = tanhf(vx);
    if (pairs) {
        float vy = ay + bias[c0 + 1];
        if (act == 1) vy = fmaxf(vy, 0.0f);
        else if (act == 2) vy = tanhf(vy);
        *(__hip_bfloat162*)(out + (long)d * HC + c0) =
            __hip_bfloat162{__float2bfloat16(vx), __float2bfloat16(vy)};
    } else {
        out[(long)d * HC + c0] = __float2bfloat16(vx);
    }
}

// ---------------- launch ----------------

extern "C" void kernel_launch(void* const* d_in, const int* in_sizes, int n_in,
                              void* d_out, int out_size, void* d_ws, size_t ws_size,
                              hipStream_t stream) {
    const float* x    = (const float*)d_in[0];
    const int*   ei   = (const int*)d_in[1];
    const float* W1   = (const float*)d_in[2];
    const float* a1s  = (const float*)d_in[3];
    const float* a1d  = (const float*)d_in[4];
    const float* b1   = (const float*)d_in[5];
    const float* W2   = (const float*)d_in[6];
    const float* a2s  = (const float*)d_in[7];
    const float* a2d  = (const float*)d_in[8];
    const float* b2   = (const float*)d_in[9];
    const float* W3   = (const float*)d_in[10];
    const float* a3s  = (const float*)d_in[11];
    const float* a3d  = (const float*)d_in[12];
    const float* b3   = (const float*)d_in[13];
    const float* Wc   = (const float*)d_in[14];
    const float* bc   = (const float*)d_in[15];

    const int F0 = 256;
    int N = in_sizes[0] / F0;          // 50000
    int E = in_sizes[1] / 2;           // 800000
    int Etot = E + N;
    const int* srcI = ei;
    const int* dstI = ei + E;

    // ---- workspace carve ----
    char* p = (char*)d_ws;
    auto alloc = [&](size_t bytes) { void* r = p; p += (bytes + 255) & ~(size_t)255; return r; };
    __hip_bfloat16* xb  = (__hip_bfloat16*)alloc((size_t)N * 256 * 2);
    __hip_bfloat16* Hb  = (__hip_bfloat16*)alloc((size_t)N * 384 * 2);
    __hip_bfloat16* O1  = (__hip_bfloat16*)alloc((size_t)N * 384 * 2);
    __hip_bfloat16* O2  = (__hip_bfloat16*)alloc((size_t)N * 128 * 2);
    __hip_bfloat16* O3  = (__hip_bfloat16*)alloc((size_t)N * 64 * 2);
    __hip_bfloat16* W1T = (__hip_bfloat16*)alloc((size_t)384 * 256 * 2);
    __hip_bfloat16* W2T = (__hip_bfloat16*)alloc((size_t)128 * 384 * 2);
    __hip_bfloat16* W3T = (__hip_bfloat16*)alloc((size_t)64 * 128 * 2);
    __hip_bfloat16* WcT = (__hip_bfloat16*)alloc((size_t)40 * 64 * 2);
    float* ebuf = (float*)alloc((size_t)Etot * 4 * 4);
    float* as_  = (float*)alloc((size_t)N * 4 * 4);
    float* ad_  = (float*)alloc((size_t)N * 4 * 4);
    float* m_   = (float*)alloc((size_t)N * 4 * 4);
    float* dn_  = (float*)alloc((size_t)N * 4 * 4);
    int* rowptr = (int*)alloc((size_t)(N + 1) * 4);
    int* cnt    = (int*)alloc((size_t)N * 4);
    int* esrc   = (int*)alloc((size_t)Etot * 4);
    int* edst   = (int*)alloc((size_t)Etot * 4);
    int* bsum   = (int*)alloc(256 * 4);

    // ---- input casts / weight prep ----
    long nx = (long)N * 256;
    cast_bf16_4<<<(int)((nx / 4 + 255) / 256), 256, 0, stream>>>(x, xb, nx);
    wtrans<<<(256 * 384 + 255) / 256, 256, 0, stream>>>(W1, W1T, 256, 384);
    wtrans<<<(384 * 128 + 255) / 256, 256, 0, stream>>>(W2, W2T, 384, 128);
    wtrans<<<(128 * 64 + 255) / 256, 256, 0, stream>>>(W3, W3T, 128, 64);
    wtrans<<<(64 * 40 + 255) / 256, 256, 0, stream>>>(Wc, WcT, 64, 40);

    // ---- CSR build ----
    int nb = (N + 255) / 256;
    zero_int<<<nb, 256, 0, stream>>>(cnt, N);
    hist_kernel<<<(Etot + 255) / 256, 256, 0, stream>>>(dstI, cnt, E, Etot);
    scan1<<<nb, 256, 0, stream>>>(cnt, rowptr, bsum, N);
    scan2<<<1, 256, 0, stream>>>(bsum, nb);
    scan3<<<nb, 256, 0, stream>>>(rowptr, bsum, cnt, N, Etot);
    fill_kernel<<<(Etot + 255) / 256, 256, 0, stream>>>(srcI, dstI, rowptr, cnt,
                                                        esrc, edst, E, Etot);

    auto run_gat = [&](const __hip_bfloat16* X, int Fin, const __hip_bfloat16* WT,
                       const float* av_s, const float* av_d, const float* bias,
                       int Hh, int C, __hip_bfloat16* Obuf, int act) {
        int HC = Hh * C;
        dim3 gg((HC + 63) / 64, (N + 63) / 64);
        gemm_bf16<<<gg, 256, 0, stream>>>(X, WT, Hb, nullptr, nullptr, N, Fin, HC);
        int nh = N * Hh;
        alpha_kernel<<<(nh + 255) / 256, 256, 0, stream>>>(Hb, av_s, av_d, as_, ad_, N, Hh, C);
        init_seg<<<(nh + 255) / 256, 256, 0, stream>>>(m_, dn_, nh);
        int eh = Etot * Hh;
        edge_max<<<(eh + 255) / 256, 256, 0, stream>>>(esrc, edst, as_, ad_, ebuf, m_, Etot, Hh);
        edge_exp<<<(eh + 255) / 256, 256, 0, stream>>>(edst, ebuf, m_, dn_, Etot, Hh);
        int pairs = (HC >= 128) ? 1 : 0;
        int T = pairs ? HC / 2 : HC;
        node_gather<<<N, T, 0, stream>>>(rowptr, esrc, Hb, ebuf, dn_, bias, Obuf, Hh, C, act, pairs);
    };

    // Layer 1: 256 -> 4x96, relu
    run_gat(xb, 256, W1T, a1s, a1d, b1, 4, 96, O1, 1);
    // Layer 2: 384 -> 1x128, tanh
    run_gat(O1, 384, W2T, a2s, a2d, b2, 1, 128, O2, 2);
    // Layer 3: 128 -> 1x64, tanh
    run_gat(O2, 128, W3T, a3s, a3d, b3, 1, 64, O3, 2);

    // Classifier: out = O3 @ Wc + bc   [N,40] f32
    float* out = (float*)d_out;
    dim3 gg((40 + 63) / 64, (N + 63) / 64);
    gemm_bf16<<<gg, 256, 0, stream>>>(O3, WcT, nullptr, out, bc, N, 64, 40);
}

// Round 4
// 536.869 us; speedup vs baseline: 4.5710x; 1.4813x over previous
//
#include <hip/hip_runtime.h>
#include <hip/hip_bf16.h>
#include <math.h>

#define NEG_SLOPE 0.2f

typedef __attribute__((ext_vector_type(8))) short short8v;   // 8 bf16
typedef __attribute__((ext_vector_type(4))) float f32x4;

__device__ __forceinline__ float bfu2f(unsigned short u) {
    return __uint_as_float((unsigned)u << 16);
}

// ---------------- casts / weight prep ----------------

__global__ void cast_bf16_4(const float* __restrict__ in, __hip_bfloat16* __restrict__ out,
                            long n) {
    long i = ((long)blockIdx.x * blockDim.x + threadIdx.x) * 4;
    if (i >= n) return;
    float4 v = *(const float4*)(in + i);
    __hip_bfloat162* o = (__hip_bfloat162*)(out + i);
    o[0] = __hip_bfloat162{__float2bfloat16(v.x), __float2bfloat16(v.y)};
    o[1] = __hip_bfloat162{__float2bfloat16(v.z), __float2bfloat16(v.w)};
}

// W [K][HC] f32 -> WT rows 0..HC-1 = [HC][K] bf16
__global__ void wtrans(const float* __restrict__ W, __hip_bfloat16* __restrict__ WT,
                       int K, int N) {
    int t = blockIdx.x * blockDim.x + threadIdx.x;
    if (t >= K * N) return;
    int n = t / K, k = t - n * K;
    WT[t] = __float2bfloat16(W[(long)k * N + n]);
}

// extra rows HC+2h (=W@a_src_h), HC+2h+1 (=W@a_dst_h)
__global__ void wext(const float* __restrict__ W, const float* __restrict__ a_src,
                     const float* __restrict__ a_dst, __hip_bfloat16* __restrict__ WT,
                     int K, int HC, int Hh, int C) {
    int t = blockIdx.x * blockDim.x + threadIdx.x;
    if (t >= 2 * Hh * K) return;
    int r = t / K, k = t - r * K;
    int h = r >> 1;
    const float* av = ((r & 1) ? a_dst : a_src) + h * C;
    const float* wp = W + (long)k * HC + h * C;
    float s = 0.f;
    for (int c = 0; c < C; ++c) s += av[c] * wp[c];
    WT[(long)(HC + r) * K + k] = __float2bfloat16(s);
}

// ---------------- MFMA bf16 GEMM with attention-projection epilogue ----------------
// C[M, 0..HC-1] = A[M,K] @ BT[0..HC-1, K]^T  (bf16 Cb, stride HC, or f32 Cf + bias)
// cols HC..Nlog-1 -> as_/ad_ f32 (col HC+2h -> as_[m,h], HC+2h+1 -> ad_[m,h])
__global__ __launch_bounds__(256) void gemm_bf16(
        const __hip_bfloat16* __restrict__ A, const __hip_bfloat16* __restrict__ BT,
        __hip_bfloat16* __restrict__ Cb, float* __restrict__ Cf,
        const float* __restrict__ bias, float* __restrict__ asv, float* __restrict__ adv,
        int M, int K, int Nlog, int HC, int Hh) {
    __shared__ __align__(16) __hip_bfloat16 As[64][40];
    __shared__ __align__(16) __hip_bfloat16 Bs[64][40];
    int t = threadIdx.x;
    int wave = t >> 6, lane = t & 63;
    int wm = wave >> 1, wn = wave & 1;
    int m0 = blockIdx.y * 64, n0 = blockIdx.x * 64;
    int lrow = lane & 15, kb = lane >> 4;

    f32x4 acc[2][2] = {};
    int srow = t >> 2, scol = (t & 3) * 8;

    for (int k0 = 0; k0 < K; k0 += 32) {
        int gr = m0 + srow;
        short8v av = {};
        if (gr < M) av = *(const short8v*)(A + (long)gr * K + k0 + scol);
        int gn = n0 + srow;
        short8v bv = {};
        if (gn < Nlog) bv = *(const short8v*)(BT + (long)gn * K + k0 + scol);
        __syncthreads();
        *(short8v*)&As[srow][scol] = av;
        *(short8v*)&Bs[srow][scol] = bv;
        __syncthreads();
        short8v a0 = *(const short8v*)&As[wm * 32 + lrow][kb * 8];
        short8v a1 = *(const short8v*)&As[wm * 32 + 16 + lrow][kb * 8];
        short8v b0 = *(const short8v*)&Bs[wn * 32 + lrow][kb * 8];
        short8v b1 = *(const short8v*)&Bs[wn * 32 + 16 + lrow][kb * 8];
        acc[0][0] = __builtin_amdgcn_mfma_f32_16x16x32_bf16(a0, b0, acc[0][0], 0, 0, 0);
        acc[0][1] = __builtin_amdgcn_mfma_f32_16x16x32_bf16(a0, b1, acc[0][1], 0, 0, 0);
        acc[1][0] = __builtin_amdgcn_mfma_f32_16x16x32_bf16(a1, b0, acc[1][0], 0, 0, 0);
        acc[1][1] = __builtin_amdgcn_mfma_f32_16x16x32_bf16(a1, b1, acc[1][1], 0, 0, 0);
    }
#pragma unroll
    for (int i = 0; i < 2; ++i)
#pragma unroll
        for (int j = 0; j < 2; ++j) {
            int col = n0 + wn * 32 + j * 16 + lrow;
            if (col >= Nlog) continue;
#pragma unroll
            for (int r = 0; r < 4; ++r) {
                int row = m0 + wm * 32 + i * 16 + kb * 4 + r;
                if (row >= M) continue;
                float v = acc[i][j][r];
                if (col < HC) {
                    if (Cf) Cf[(long)row * HC + col] = v + (bias ? bias[col] : 0.f);
                    else Cb[(long)row * HC + col] = __float2bfloat16(v);
                } else {
                    int f = col - HC, h = f >> 1;
                    if (f & 1) adv[row * Hh + h] = v;
                    else       asv[row * Hh + h] = v;
                }
            }
        }
}

// ---------------- CSR build ----------------

__global__ void hist_kernel(const int* __restrict__ dst, int* __restrict__ cnt,
                            int E, int Etot) {
    int e = blockIdx.x * blockDim.x + threadIdx.x;
    if (e >= Etot) return;
    int d = (e < E) ? dst[e] : (e - E);
    atomicAdd(&cnt[d], 1);
}

__global__ void zero_int(int* __restrict__ p, int n) {
    int t = blockIdx.x * blockDim.x + threadIdx.x;
    if (t < n) p[t] = 0;
}

__global__ void scan1(const int* __restrict__ cnt, int* __restrict__ rowptr,
                      int* __restrict__ bsum, int n) {
    __shared__ int s[256];
    int i = blockIdx.x * 256 + threadIdx.x;
    int v = (i < n) ? cnt[i] : 0;
    s[threadIdx.x] = v;
    __syncthreads();
    for (int off = 1; off < 256; off <<= 1) {
        int t = (threadIdx.x >= off) ? s[threadIdx.x - off] : 0;
        __syncthreads();
        s[threadIdx.x] += t;
        __syncthreads();
    }
    if (i < n) rowptr[i] = s[threadIdx.x] - v;
    if (threadIdx.x == 255) bsum[blockIdx.x] = s[255];
}

__global__ void scan2(int* __restrict__ bsum, int nb) {
    __shared__ int s[256];
    int v = (threadIdx.x < nb) ? bsum[threadIdx.x] : 0;
    s[threadIdx.x] = v;
    __syncthreads();
    for (int off = 1; off < 256; off <<= 1) {
        int t = (threadIdx.x >= off) ? s[threadIdx.x - off] : 0;
        __syncthreads();
        s[threadIdx.x] += t;
        __syncthreads();
    }
    if (threadIdx.x < nb) bsum[threadIdx.x] = s[threadIdx.x] - v;
}

__global__ void scan3(int* __restrict__ rowptr, const int* __restrict__ bsum,
                      int* __restrict__ cnt, int n, int Etot) {
    int i = blockIdx.x * 256 + threadIdx.x;
    if (i < n) {
        rowptr[i] += bsum[blockIdx.x];
        cnt[i] = 0;
    }
    if (i == 0) rowptr[n] = Etot;
}

__global__ void fill_kernel(const int* __restrict__ src, const int* __restrict__ dst,
                            const int* __restrict__ rowptr, int* __restrict__ cursor,
                            int* __restrict__ esrc, int E, int Etot) {
    int e = blockIdx.x * blockDim.x + threadIdx.x;
    if (e >= Etot) return;
    int s = (e < E) ? src[e] : (e - E);
    int d = (e < E) ? dst[e] : (e - E);
    int pos = atomicAdd(&cursor[d], 1);
    esrc[rowptr[d] + pos] = s;
}

// ---------------- fused softmax + gather ----------------
// one block per dst node; online (flash-style) segment softmax over CSR chunk(64)
// each thread owns 4 contiguous channels; blockDim = HC/4 * EPB
__global__ void gat_gather(const int* __restrict__ rowptr, const int* __restrict__ esrc,
                           const __hip_bfloat16* __restrict__ H,
                           const float* __restrict__ asv, const float* __restrict__ adv,
                           const float* __restrict__ bias, __hip_bfloat16* __restrict__ out,
                           int Hh, int C, int act) {
    int d = blockIdx.x;
    int begin = rowptr[d], end = rowptr[d + 1];
    int HC = Hh * C;
    int TPE = HC >> 2;              // threads covering one edge's channels
    int EPB = blockDim.x / TPE;     // edges processed in parallel
    int t = threadIdx.x;

    __shared__ int   sSrc[64];
    __shared__ float sLog[4 * 64];   // [h][k]
    __shared__ float sRed[4 * 64];
    __shared__ float sP[64 * 4];     // [k][h]
    __shared__ float sAd[4], sM[4], sS[4], sScale[4], sMnew[4];

    if (t < Hh) { sAd[t] = adv[d * Hh + t]; sM[t] = -3.0e38f; sS[t] = 0.f; }

    int sub = t / TPE;
    int cq  = (t - sub * TPE) * 4;   // channel base (4 contiguous, same head)
    int hc  = cq / C;
    float a0 = 0.f, a1 = 0.f, a2 = 0.f, a3 = 0.f;
    __syncthreads();

    for (int chunk = begin; chunk < end; chunk += 64) {
        int n = end - chunk; if (n > 64) n = 64;
        if (t < n) sSrc[t] = esrc[chunk + t];
        __syncthreads();
        // logits
        for (int idx = t; idx < (Hh << 6); idx += blockDim.x) {
            int h = idx >> 6, k = idx & 63;
            float v = -1e30f;
            if (k < n) {
                v = asv[sSrc[k] * Hh + h] + sAd[h];
                v = (v > 0.f) ? v : NEG_SLOPE * v;
                sLog[idx] = v;
            }
            sRed[idx] = v;
        }
        __syncthreads();
        // per-head max
        for (int off = 32; off > 0; off >>= 1) {
            for (int idx = t; idx < Hh * off; idx += blockDim.x) {
                int h = idx / off, k = idx - h * off;
                float x0 = sRed[(h << 6) + k], x1 = sRed[(h << 6) + k + off];
                sRed[(h << 6) + k] = x0 > x1 ? x0 : x1;
            }
            __syncthreads();
        }
        if (t < Hh) {
            float mo = sM[t];
            float mn = fmaxf(mo, sRed[t << 6]);
            sMnew[t] = mn; sScale[t] = __expf(mo - mn); sM[t] = mn;
        }
        __syncthreads();
        // p = exp(log - m)
        for (int idx = t; idx < (Hh << 6); idx += blockDim.x) {
            int h = idx >> 6, k = idx & 63;
            float p = 0.f;
            if (k < n) { p = __expf(sLog[idx] - sMnew[h]); sP[k * Hh + h] = p; }
            sRed[idx] = p;
        }
        __syncthreads();
        // per-head sum
        for (int off = 32; off > 0; off >>= 1) {
            for (int idx = t; idx < Hh * off; idx += blockDim.x) {
                int h = idx / off, k = idx - h * off;
                sRed[(h << 6) + k] += sRed[(h << 6) + k + off];
            }
            __syncthreads();
        }
        if (t < Hh) sS[t] = sS[t] * sScale[t] + sRed[t << 6];
        // rescale accumulator, then gather this chunk
        float sc = sScale[hc];
        a0 *= sc; a1 *= sc; a2 *= sc; a3 *= sc;
        for (int k = sub; k < n; k += EPB) {
            float p = sP[k * Hh + hc];
            const ushort4 v = *(const ushort4*)(H + (long)sSrc[k] * HC + cq);
            a0 += p * bfu2f(v.x); a1 += p * bfu2f(v.y);
            a2 += p * bfu2f(v.z); a3 += p * bfu2f(v.w);
        }
        __syncthreads();
    }
    // EPB-way partial sums: lanes (sub>0) accumulated disjoint edges of same channels
    if (EPB > 1) {
        // reduce across sub groups via LDS (reuse sRed area; HC*? <= 384 floats*?)
        // store partials: layout [sub][TPE] per channel-quad element -> 4 arrays flattened
        // simple approach: atomic-free tree over sub using sLog/sRed buffers (size 4*64=256 < TPE*... )
        // fall back: each sub>0 thread adds into LDS, sub==0 reads. TPE <= 96, EPB <= 4.
        __shared__ float sAcc[4 * 96 * 3];   // up to (EPB-1)*TPE*4 floats
        if (sub > 0) {
            int b = ((sub - 1) * TPE + (cq >> 2)) * 4;
            sAcc[b] = a0; sAcc[b + 1] = a1; sAcc[b + 2] = a2; sAcc[b + 3] = a3;
        }
        __syncthreads();
        if (sub == 0) {
            for (int s2 = 0; s2 < EPB - 1; ++s2) {
                int b = (s2 * TPE + (cq >> 2)) * 4;
                a0 += sAcc[b]; a1 += sAcc[b + 1]; a2 += sAcc[b + 2]; a3 += sAcc[b + 3];
            }
        }
    }
    if (sub == 0) {
        float dnm = sS[hc] + 1e-16f;
        float r0 = a0 / dnm + bias[cq];
        float r1 = a1 / dnm + bias[cq + 1];
        float r2 = a2 / dnm + bias[cq + 2];
        float r3 = a3 / dnm + bias[cq + 3];
        if (act == 1) {
            r0 = fmaxf(r0, 0.f); r1 = fmaxf(r1, 0.f);
            r2 = fmaxf(r2, 0.f); r3 = fmaxf(r3, 0.f);
        } else if (act == 2) {
            r0 = tanhf(r0); r1 = tanhf(r1); r2 = tanhf(r2); r3 = tanhf(r3);
        }
        __hip_bfloat162* op = (__hip_bfloat162*)(out + (long)d * HC + cq);
        op[0] = __hip_bfloat162{__float2bfloat16(r0), __float2bfloat16(r1)};
        op[1] = __hip_bfloat162{__float2bfloat16(r2), __float2bfloat16(r3)};
    }
}

// ---------------- launch ----------------

extern "C" void kernel_launch(void* const* d_in, const int* in_sizes, int n_in,
                              void* d_out, int out_size, void* d_ws, size_t ws_size,
                              hipStream_t stream) {
    const float* x    = (const float*)d_in[0];
    const int*   ei   = (const int*)d_in[1];
    const float* W1   = (const float*)d_in[2];
    const float* a1s  = (const float*)d_in[3];
    const float* a1d  = (const float*)d_in[4];
    const float* b1   = (const float*)d_in[5];
    const float* W2   = (const float*)d_in[6];
    const float* a2s  = (const float*)d_in[7];
    const float* a2d  = (const float*)d_in[8];
    const float* b2   = (const float*)d_in[9];
    const float* W3   = (const float*)d_in[10];
    const float* a3s  = (const float*)d_in[11];
    const float* a3d  = (const float*)d_in[12];
    const float* b3   = (const float*)d_in[13];
    const float* Wc   = (const float*)d_in[14];
    const float* bc   = (const float*)d_in[15];

    const int F0 = 256;
    int N = in_sizes[0] / F0;          // 50000
    int E = in_sizes[1] / 2;           // 800000
    int Etot = E + N;
    const int* srcI = ei;
    const int* dstI = ei + E;

    // ---- workspace carve ----
    char* p = (char*)d_ws;
    auto alloc = [&](size_t bytes) { void* r = p; p += (bytes + 255) & ~(size_t)255; return r; };
    __hip_bfloat16* xb  = (__hip_bfloat16*)alloc((size_t)N * 256 * 2);
    __hip_bfloat16* Hb  = (__hip_bfloat16*)alloc((size_t)N * 384 * 2);
    __hip_bfloat16* O1  = (__hip_bfloat16*)alloc((size_t)N * 384 * 2);
    __hip_bfloat16* O2  = (__hip_bfloat16*)alloc((size_t)N * 128 * 2);
    __hip_bfloat16* O3  = (__hip_bfloat16*)alloc((size_t)N * 64 * 2);
    __hip_bfloat16* W1T = (__hip_bfloat16*)alloc((size_t)(384 + 8) * 256 * 2);
    __hip_bfloat16* W2T = (__hip_bfloat16*)alloc((size_t)(128 + 2) * 384 * 2);
    __hip_bfloat16* W3T = (__hip_bfloat16*)alloc((size_t)(64 + 2) * 128 * 2);
    __hip_bfloat16* WcT = (__hip_bfloat16*)alloc((size_t)40 * 64 * 2);
    float* as_  = (float*)alloc((size_t)N * 4 * 4);
    float* ad_  = (float*)alloc((size_t)N * 4 * 4);
    int* rowptr = (int*)alloc((size_t)(N + 1) * 4);
    int* cnt    = (int*)alloc((size_t)N * 4);
    int* esrc   = (int*)alloc((size_t)Etot * 4);
    int* bsum   = (int*)alloc(256 * 4);

    // ---- input casts / weight prep ----
    long nx = (long)N * 256;
    cast_bf16_4<<<(int)((nx / 4 + 255) / 256), 256, 0, stream>>>(x, xb, nx);
    wtrans<<<(256 * 384 + 255) / 256, 256, 0, stream>>>(W1, W1T, 256, 384);
    wtrans<<<(384 * 128 + 255) / 256, 256, 0, stream>>>(W2, W2T, 384, 128);
    wtrans<<<(128 * 64 + 255) / 256, 256, 0, stream>>>(W3, W3T, 128, 64);
    wtrans<<<(64 * 40 + 255) / 256, 256, 0, stream>>>(Wc, WcT, 64, 40);
    wext<<<(8 * 256 + 255) / 256, 256, 0, stream>>>(W1, a1s, a1d, W1T, 256, 384, 4, 96);
    wext<<<(2 * 384 + 255) / 256, 256, 0, stream>>>(W2, a2s, a2d, W2T, 384, 128, 1, 128);
    wext<<<(2 * 128 + 255) / 256, 256, 0, stream>>>(W3, a3s, a3d, W3T, 128, 64, 1, 64);

    // ---- CSR build ----
    int nb = (N + 255) / 256;
    zero_int<<<nb, 256, 0, stream>>>(cnt, N);
    hist_kernel<<<(Etot + 255) / 256, 256, 0, stream>>>(dstI, cnt, E, Etot);
    scan1<<<nb, 256, 0, stream>>>(cnt, rowptr, bsum, N);
    scan2<<<1, 256, 0, stream>>>(bsum, nb);
    scan3<<<nb, 256, 0, stream>>>(rowptr, bsum, cnt, N, Etot);
    fill_kernel<<<(Etot + 255) / 256, 256, 0, stream>>>(srcI, dstI, rowptr, cnt, esrc, E, Etot);

    auto run_gat = [&](const __hip_bfloat16* X, int Fin, const __hip_bfloat16* WT,
                       const float* bias, int Hh, int C, __hip_bfloat16* Obuf,
                       int act, int block) {
        int HC = Hh * C;
        int Nlog = HC + 2 * Hh;
        dim3 gg((Nlog + 63) / 64, (N + 63) / 64);
        gemm_bf16<<<gg, 256, 0, stream>>>(X, WT, Hb, nullptr, nullptr, as_, ad_,
                                          N, Fin, Nlog, HC, Hh);
        gat_gather<<<N, block, 0, stream>>>(rowptr, esrc, Hb, as_, ad_, bias, Obuf,
                                            Hh, C, act);
    };

    // Layer 1: 256 -> 4x96, relu   (block 192 = 96 TPE * 2 EPB)
    run_gat(xb, 256, W1T, b1, 4, 96, O1, 1, 192);
    // Layer 2: 384 -> 1x128, tanh  (block 64 = 32 TPE * 2 EPB)
    run_gat(O1, 384, W2T, b2, 1, 128, O2, 2, 64);
    // Layer 3: 128 -> 1x64, tanh   (block 64 = 16 TPE * 4 EPB)
    run_gat(O2, 128, W3T, b3, 1, 64, O3, 2, 64);

    // Classifier: out = O3 @ Wc + bc   [N,40] f32
    float* out = (float*)d_out;
    dim3 gg((40 + 63) / 64, (N + 63) / 64);
    gemm_bf16<<<gg, 256, 0, stream>>>(O3, WcT, nullptr, out, bc, as_, ad_,
                                      N, 64, 40, 40, 0);
}

// Round 5
// 466.974 us; speedup vs baseline: 5.2552x; 1.1497x over previous
//
#include <hip/hip_runtime.h>
#include <hip/hip_bf16.h>
#include <math.h>

#define NEG_SLOPE 0.2f

typedef __attribute__((ext_vector_type(8))) short short8v;   // 8 bf16
typedef __attribute__((ext_vector_type(4))) float f32x4;

__device__ __forceinline__ float bfu2f(unsigned short u) {
    return __uint_as_float((unsigned)u << 16);
}

// ---------------- casts / weight prep ----------------

__global__ void cast_bf16_4(const float* __restrict__ in, __hip_bfloat16* __restrict__ out,
                            long n) {
    long i = ((long)blockIdx.x * blockDim.x + threadIdx.x) * 4;
    if (i >= n) return;
    float4 v = *(const float4*)(in + i);
    __hip_bfloat162* o = (__hip_bfloat162*)(out + i);
    o[0] = __hip_bfloat162{__float2bfloat16(v.x), __float2bfloat16(v.y)};
    o[1] = __hip_bfloat162{__float2bfloat16(v.z), __float2bfloat16(v.w)};
}

// W [K][HC] f32 -> WT rows 0..HC-1 = [HC][K] bf16
__global__ void wtrans(const float* __restrict__ W, __hip_bfloat16* __restrict__ WT,
                       int K, int N) {
    int t = blockIdx.x * blockDim.x + threadIdx.x;
    if (t >= K * N) return;
    int n = t / K, k = t - n * K;
    WT[t] = __float2bfloat16(W[(long)k * N + n]);
}

// extra rows HC+2h (=W@a_src_h), HC+2h+1 (=W@a_dst_h)
__global__ void wext(const float* __restrict__ W, const float* __restrict__ a_src,
                     const float* __restrict__ a_dst, __hip_bfloat16* __restrict__ WT,
                     int K, int HC, int Hh, int C) {
    int t = blockIdx.x * blockDim.x + threadIdx.x;
    if (t >= 2 * Hh * K) return;
    int r = t / K, k = t - r * K;
    int h = r >> 1;
    const float* av = ((r & 1) ? a_dst : a_src) + h * C;
    const float* wp = W + (long)k * HC + h * C;
    float s = 0.f;
    for (int c = 0; c < C; ++c) s += av[c] * wp[c];
    WT[(long)(HC + r) * K + k] = __float2bfloat16(s);
}

// ---------------- MFMA bf16 GEMM with attention-projection epilogue ----------------
__global__ __launch_bounds__(256) void gemm_bf16(
        const __hip_bfloat16* __restrict__ A, const __hip_bfloat16* __restrict__ BT,
        __hip_bfloat16* __restrict__ Cb, float* __restrict__ Cf,
        const float* __restrict__ bias, float* __restrict__ asv, float* __restrict__ adv,
        int M, int K, int Nlog, int HC, int Hh) {
    __shared__ __align__(16) __hip_bfloat16 As[64][40];
    __shared__ __align__(16) __hip_bfloat16 Bs[64][40];
    int t = threadIdx.x;
    int wave = t >> 6, lane = t & 63;
    int wm = wave >> 1, wn = wave & 1;
    int m0 = blockIdx.y * 64, n0 = blockIdx.x * 64;
    int lrow = lane & 15, kb = lane >> 4;

    f32x4 acc[2][2] = {};
    int srow = t >> 2, scol = (t & 3) * 8;

    for (int k0 = 0; k0 < K; k0 += 32) {
        int gr = m0 + srow;
        short8v av = {};
        if (gr < M) av = *(const short8v*)(A + (long)gr * K + k0 + scol);
        int gn = n0 + srow;
        short8v bv = {};
        if (gn < Nlog) bv = *(const short8v*)(BT + (long)gn * K + k0 + scol);
        __syncthreads();
        *(short8v*)&As[srow][scol] = av;
        *(short8v*)&Bs[srow][scol] = bv;
        __syncthreads();
        short8v a0 = *(const short8v*)&As[wm * 32 + lrow][kb * 8];
        short8v a1 = *(const short8v*)&As[wm * 32 + 16 + lrow][kb * 8];
        short8v b0 = *(const short8v*)&Bs[wn * 32 + lrow][kb * 8];
        short8v b1 = *(const short8v*)&Bs[wn * 32 + 16 + lrow][kb * 8];
        acc[0][0] = __builtin_amdgcn_mfma_f32_16x16x32_bf16(a0, b0, acc[0][0], 0, 0, 0);
        acc[0][1] = __builtin_amdgcn_mfma_f32_16x16x32_bf16(a0, b1, acc[0][1], 0, 0, 0);
        acc[1][0] = __builtin_amdgcn_mfma_f32_16x16x32_bf16(a1, b0, acc[1][0], 0, 0, 0);
        acc[1][1] = __builtin_amdgcn_mfma_f32_16x16x32_bf16(a1, b1, acc[1][1], 0, 0, 0);
    }
#pragma unroll
    for (int i = 0; i < 2; ++i)
#pragma unroll
        for (int j = 0; j < 2; ++j) {
            int col = n0 + wn * 32 + j * 16 + lrow;
            if (col >= Nlog) continue;
#pragma unroll
            for (int r = 0; r < 4; ++r) {
                int row = m0 + wm * 32 + i * 16 + kb * 4 + r;
                if (row >= M) continue;
                float v = acc[i][j][r];
                if (col < HC) {
                    if (Cf) Cf[(long)row * HC + col] = v + (bias ? bias[col] : 0.f);
                    else Cb[(long)row * HC + col] = __float2bfloat16(v);
                } else {
                    int f = col - HC, h = f >> 1;
                    if (f & 1) adv[row * Hh + h] = v;
                    else       asv[row * Hh + h] = v;
                }
            }
        }
}

// ---------------- CSR build ----------------

__global__ void hist_kernel(const int* __restrict__ dst, int* __restrict__ cnt,
                            int E, int Etot) {
    int e = blockIdx.x * blockDim.x + threadIdx.x;
    if (e >= Etot) return;
    int d = (e < E) ? dst[e] : (e - E);
    atomicAdd(&cnt[d], 1);
}

__global__ void zero_int(int* __restrict__ p, int n) {
    int t = blockIdx.x * blockDim.x + threadIdx.x;
    if (t < n) p[t] = 0;
}

__global__ void scan1(const int* __restrict__ cnt, int* __restrict__ rowptr,
                      int* __restrict__ bsum, int n) {
    __shared__ int s[256];
    int i = blockIdx.x * 256 + threadIdx.x;
    int v = (i < n) ? cnt[i] : 0;
    s[threadIdx.x] = v;
    __syncthreads();
    for (int off = 1; off < 256; off <<= 1) {
        int t = (threadIdx.x >= off) ? s[threadIdx.x - off] : 0;
        __syncthreads();
        s[threadIdx.x] += t;
        __syncthreads();
    }
    if (i < n) rowptr[i] = s[threadIdx.x] - v;
    if (threadIdx.x == 255) bsum[blockIdx.x] = s[255];
}

__global__ void scan2(int* __restrict__ bsum, int nb) {
    __shared__ int s[256];
    int v = (threadIdx.x < nb) ? bsum[threadIdx.x] : 0;
    s[threadIdx.x] = v;
    __syncthreads();
    for (int off = 1; off < 256; off <<= 1) {
        int t = (threadIdx.x >= off) ? s[threadIdx.x - off] : 0;
        __syncthreads();
        s[threadIdx.x] += t;
        __syncthreads();
    }
    if (threadIdx.x < nb) bsum[threadIdx.x] = s[threadIdx.x] - v;
}

__global__ void scan3(int* __restrict__ rowptr, const int* __restrict__ bsum,
                      int* __restrict__ cnt, int n, int Etot) {
    int i = blockIdx.x * 256 + threadIdx.x;
    if (i < n) {
        rowptr[i] += bsum[blockIdx.x];
        cnt[i] = 0;
    }
    if (i == 0) rowptr[n] = Etot;
}

__global__ void fill_kernel(const int* __restrict__ src, const int* __restrict__ dst,
                            const int* __restrict__ rowptr, int* __restrict__ cursor,
                            int* __restrict__ esrc, int E, int Etot) {
    int e = blockIdx.x * blockDim.x + threadIdx.x;
    if (e >= Etot) return;
    int s = (e < E) ? src[e] : (e - E);
    int d = (e < E) ? dst[e] : (e - E);
    int pos = atomicAdd(&cursor[d], 1);
    esrc[rowptr[d] + pos] = s;
}

// ---------------- fused softmax + gather (wave-register softmax) ----------------
// one block per dst node. Wave 0 does the segment softmax for a 64-edge chunk
// entirely in registers (per-head shfl_xor butterflies, online rescale);
// all threads then gather: thread owns 4 contiguous channels, EPB edge-slices.
template <int HH>
__global__ void gat_gather(const int* __restrict__ rowptr, const int* __restrict__ esrc,
                           const __hip_bfloat16* __restrict__ H,
                           const float* __restrict__ asv, const float* __restrict__ adv,
                           const float* __restrict__ bias, __hip_bfloat16* __restrict__ out,
                           int C, int act) {
    const int d = blockIdx.x;
    const int begin = rowptr[d], end = rowptr[d + 1];
    const int HC = HH * C;
    const int TPE = HC >> 2;
    const int EPB = blockDim.x / TPE;
    const int t = threadIdx.x;

    __shared__ int   sSrc[64];
    __shared__ float sAl[HH * 64];     // [h][k]
    __shared__ float sScale[HH];
    __shared__ float sDen[HH];
    __shared__ float sPart[4 * 96 * 3]; // [c][sub-1][tq], worst case

    const int sub = t / TPE;
    const int tq  = t - sub * TPE;
    const int cq  = tq * 4;            // 4 contiguous channels, same head
    const int hc  = cq / C;
    float a0 = 0.f, a1 = 0.f, a2 = 0.f, a3 = 0.f;

    // wave-0 uniform online-softmax state
    float m_run[HH], s_run[HH];
#pragma unroll
    for (int h = 0; h < HH; ++h) { m_run[h] = -3.0e38f; s_run[h] = 0.f; }
    float adn[HH];
    if (t < 64) {
#pragma unroll
        for (int h = 0; h < HH; ++h) adn[h] = adv[d * HH + h];
    }

    for (int chunk = begin; chunk < end; chunk += 64) {
        int n = end - chunk; if (n > 64) n = 64;
        __syncthreads();                       // protect sSrc/sAl reuse
        if (t < n) sSrc[t] = esrc[chunk + t];
        __syncthreads();

        if (t < 64) {
            float lg[HH];
            if (t < n) {
                int s = sSrc[t];
                if (HH == 4) {
                    float4 av4 = *(const float4*)(asv + s * 4);
                    float vv[4] = {av4.x, av4.y, av4.z, av4.w};
#pragma unroll
                    for (int h = 0; h < HH; ++h) {
                        float v = vv[h] + adn[h];
                        lg[h] = (v > 0.f) ? v : NEG_SLOPE * v;
                    }
                } else {
                    float v = asv[s] + adn[0];
                    lg[0] = (v > 0.f) ? v : NEG_SLOPE * v;
                }
            } else {
#pragma unroll
                for (int h = 0; h < HH; ++h) lg[h] = -3.0e38f;
            }
            // per-head 64-lane butterfly max
            float cm[HH], p[HH], cs[HH];
#pragma unroll
            for (int h = 0; h < HH; ++h) {
                cm[h] = lg[h];
#pragma unroll
                for (int msk = 1; msk < 64; msk <<= 1)
                    cm[h] = fmaxf(cm[h], __shfl_xor(cm[h], msk));
            }
#pragma unroll
            for (int h = 0; h < HH; ++h) {
                p[h] = (t < n) ? __expf(lg[h] - cm[h]) : 0.f;
                cs[h] = p[h];
#pragma unroll
                for (int msk = 1; msk < 64; msk <<= 1)
                    cs[h] += __shfl_xor(cs[h], msk);
            }
            // online update (uniform across wave 0)
            float sc[HH], padj[HH];
#pragma unroll
            for (int h = 0; h < HH; ++h) {
                float mn = fmaxf(m_run[h], cm[h]);
                sc[h]   = __expf(m_run[h] - mn);
                padj[h] = __expf(cm[h] - mn);
                s_run[h] = s_run[h] * sc[h] + cs[h] * padj[h];
                m_run[h] = mn;
            }
#pragma unroll
            for (int h = 0; h < HH; ++h) sAl[h * 64 + t] = p[h] * padj[h];
            if (t == 0) {
#pragma unroll
                for (int h = 0; h < HH; ++h) sScale[h] = sc[h];
            }
        }
        __syncthreads();

        float scv = sScale[hc];
        a0 *= scv; a1 *= scv; a2 *= scv; a3 *= scv;
        for (int k = sub; k < n; k += EPB) {
            float p = sAl[hc * 64 + k];
            const ushort4 v = *(const ushort4*)(H + (long)sSrc[k] * HC + cq);
            a0 += p * bfu2f(v.x); a1 += p * bfu2f(v.y);
            a2 += p * bfu2f(v.z); a3 += p * bfu2f(v.w);
        }
    }
    if (t == 0) {
#pragma unroll
        for (int h = 0; h < HH; ++h) sDen[h] = s_run[h] + 1e-16f;
    }
    __syncthreads();

    if (EPB > 1) {
        if (sub > 0) {
            int b = (sub - 1) * TPE + tq;
            int stride = (EPB - 1) * TPE;
            sPart[b] = a0; sPart[stride + b] = a1;
            sPart[2 * stride + b] = a2; sPart[3 * stride + b] = a3;
        }
        __syncthreads();
        if (sub == 0) {
            int stride = (EPB - 1) * TPE;
            for (int s2 = 0; s2 < EPB - 1; ++s2) {
                int b = s2 * TPE + tq;
                a0 += sPart[b]; a1 += sPart[stride + b];
                a2 += sPart[2 * stride + b]; a3 += sPart[3 * stride + b];
            }
        }
    }
    if (sub == 0) {
        float dnm = sDen[hc];
        float r0 = a0 / dnm + bias[cq];
        float r1 = a1 / dnm + bias[cq + 1];
        float r2 = a2 / dnm + bias[cq + 2];
        float r3 = a3 / dnm + bias[cq + 3];
        if (act == 1) {
            r0 = fmaxf(r0, 0.f); r1 = fmaxf(r1, 0.f);
            r2 = fmaxf(r2, 0.f); r3 = fmaxf(r3, 0.f);
        } else if (act == 2) {
            r0 = tanhf(r0); r1 = tanhf(r1); r2 = tanhf(r2); r3 = tanhf(r3);
        }
        __hip_bfloat162* op = (__hip_bfloat162*)(out + (long)d * HC + cq);
        op[0] = __hip_bfloat162{__float2bfloat16(r0), __float2bfloat16(r1)};
        op[1] = __hip_bfloat162{__float2bfloat16(r2), __float2bfloat16(r3)};
    }
}

// ---------------- launch ----------------

extern "C" void kernel_launch(void* const* d_in, const int* in_sizes, int n_in,
                              void* d_out, int out_size, void* d_ws, size_t ws_size,
                              hipStream_t stream) {
    const float* x    = (const float*)d_in[0];
    const int*   ei   = (const int*)d_in[1];
    const float* W1   = (const float*)d_in[2];
    const float* a1s  = (const float*)d_in[3];
    const float* a1d  = (const float*)d_in[4];
    const float* b1   = (const float*)d_in[5];
    const float* W2   = (const float*)d_in[6];
    const float* a2s  = (const float*)d_in[7];
    const float* a2d  = (const float*)d_in[8];
    const float* b2   = (const float*)d_in[9];
    const float* W3   = (const float*)d_in[10];
    const float* a3s  = (const float*)d_in[11];
    const float* a3d  = (const float*)d_in[12];
    const float* b3   = (const float*)d_in[13];
    const float* Wc   = (const float*)d_in[14];
    const float* bc   = (const float*)d_in[15];

    const int F0 = 256;
    int N = in_sizes[0] / F0;          // 50000
    int E = in_sizes[1] / 2;           // 800000
    int Etot = E + N;
    const int* srcI = ei;
    const int* dstI = ei + E;

    // ---- workspace carve ----
    char* p = (char*)d_ws;
    auto alloc = [&](size_t bytes) { void* r = p; p += (bytes + 255) & ~(size_t)255; return r; };
    __hip_bfloat16* xb  = (__hip_bfloat16*)alloc((size_t)N * 256 * 2);
    __hip_bfloat16* Hb  = (__hip_bfloat16*)alloc((size_t)N * 384 * 2);
    __hip_bfloat16* O1  = (__hip_bfloat16*)alloc((size_t)N * 384 * 2);
    __hip_bfloat16* O2  = (__hip_bfloat16*)alloc((size_t)N * 128 * 2);
    __hip_bfloat16* O3  = (__hip_bfloat16*)alloc((size_t)N * 64 * 2);
    __hip_bfloat16* W1T = (__hip_bfloat16*)alloc((size_t)(384 + 8) * 256 * 2);
    __hip_bfloat16* W2T = (__hip_bfloat16*)alloc((size_t)(128 + 2) * 384 * 2);
    __hip_bfloat16* W3T = (__hip_bfloat16*)alloc((size_t)(64 + 2) * 128 * 2);
    __hip_bfloat16* WcT = (__hip_bfloat16*)alloc((size_t)40 * 64 * 2);
    float* as_  = (float*)alloc((size_t)N * 4 * 4);
    float* ad_  = (float*)alloc((size_t)N * 4 * 4);
    int* rowptr = (int*)alloc((size_t)(N + 1) * 4);
    int* cnt    = (int*)alloc((size_t)N * 4);
    int* esrc   = (int*)alloc((size_t)Etot * 4);
    int* bsum   = (int*)alloc(256 * 4);

    // ---- input casts / weight prep ----
    long nx = (long)N * 256;
    cast_bf16_4<<<(int)((nx / 4 + 255) / 256), 256, 0, stream>>>(x, xb, nx);
    wtrans<<<(256 * 384 + 255) / 256, 256, 0, stream>>>(W1, W1T, 256, 384);
    wtrans<<<(384 * 128 + 255) / 256, 256, 0, stream>>>(W2, W2T, 384, 128);
    wtrans<<<(128 * 64 + 255) / 256, 256, 0, stream>>>(W3, W3T, 128, 64);
    wtrans<<<(64 * 40 + 255) / 256, 256, 0, stream>>>(Wc, WcT, 64, 40);
    wext<<<(8 * 256 + 255) / 256, 256, 0, stream>>>(W1, a1s, a1d, W1T, 256, 384, 4, 96);
    wext<<<(2 * 384 + 255) / 256, 256, 0, stream>>>(W2, a2s, a2d, W2T, 384, 128, 1, 128);
    wext<<<(2 * 128 + 255) / 256, 256, 0, stream>>>(W3, a3s, a3d, W3T, 128, 64, 1, 64);

    // ---- CSR build ----
    int nb = (N + 255) / 256;
    zero_int<<<nb, 256, 0, stream>>>(cnt, N);
    hist_kernel<<<(Etot + 255) / 256, 256, 0, stream>>>(dstI, cnt, E, Etot);
    scan1<<<nb, 256, 0, stream>>>(cnt, rowptr, bsum, N);
    scan2<<<1, 256, 0, stream>>>(bsum, nb);
    scan3<<<nb, 256, 0, stream>>>(rowptr, bsum, cnt, N, Etot);
    fill_kernel<<<(Etot + 255) / 256, 256, 0, stream>>>(srcI, dstI, rowptr, cnt, esrc, E, Etot);

    auto run_gemm = [&](const __hip_bfloat16* X, int Fin, const __hip_bfloat16* WT,
                        int Hh, int C) {
        int HC = Hh * C;
        int Nlog = HC + 2 * Hh;
        dim3 gg((Nlog + 63) / 64, (N + 63) / 64);
        gemm_bf16<<<gg, 256, 0, stream>>>(X, WT, Hb, nullptr, nullptr, as_, ad_,
                                          N, Fin, Nlog, HC, Hh);
    };

    // Layer 1: 256 -> 4x96, relu   (block 192 = 96 TPE * 2 EPB)
    run_gemm(xb, 256, W1T, 4, 96);
    gat_gather<4><<<N, 192, 0, stream>>>(rowptr, esrc, Hb, as_, ad_, b1, O1, 96, 1);
    // Layer 2: 384 -> 1x128, tanh  (block 64 = 32 TPE * 2 EPB)
    run_gemm(O1, 384, W2T, 1, 128);
    gat_gather<1><<<N, 64, 0, stream>>>(rowptr, esrc, Hb, as_, ad_, b2, O2, 128, 2);
    // Layer 3: 128 -> 1x64, tanh   (block 64 = 16 TPE * 4 EPB)
    run_gemm(O2, 128, W3T, 1, 64);
    gat_gather<1><<<N, 64, 0, stream>>>(rowptr, esrc, Hb, as_, ad_, b3, O3, 64, 2);

    // Classifier: out = O3 @ Wc + bc   [N,40] f32
    float* out = (float*)d_out;
    dim3 gg((40 + 63) / 64, (N + 63) / 64);
    gemm_bf16<<<gg, 256, 0, stream>>>(O3, WcT, nullptr, out, bc, as_, ad_,
                                      N, 64, 40, 40, 0);
}

// Round 6
// 432.631 us; speedup vs baseline: 5.6724x; 1.0794x over previous
//
#include <hip/hip_runtime.h>
#include <hip/hip_bf16.h>
#include <math.h>

#define NEG_SLOPE 0.2f

typedef __attribute__((ext_vector_type(8))) short short8v;   // 8 bf16
typedef __attribute__((ext_vector_type(4))) float f32x4;

__device__ __forceinline__ float bfu2f(unsigned short u) {
    return __uint_as_float((unsigned)u << 16);
}

// ---------------- casts / weight prep ----------------

__global__ void cast_bf16_4(const float* __restrict__ in, __hip_bfloat16* __restrict__ out,
                            long n) {
    long i = ((long)blockIdx.x * blockDim.x + threadIdx.x) * 4;
    if (i >= n) return;
    float4 v = *(const float4*)(in + i);
    __hip_bfloat162* o = (__hip_bfloat162*)(out + i);
    o[0] = __hip_bfloat162{__float2bfloat16(v.x), __float2bfloat16(v.y)};
    o[1] = __hip_bfloat162{__float2bfloat16(v.z), __float2bfloat16(v.w)};
}

// W [K][HC] f32 -> WT rows 0..HC-1 = [HC][K] bf16
__global__ void wtrans(const float* __restrict__ W, __hip_bfloat16* __restrict__ WT,
                       int K, int N) {
    int t = blockIdx.x * blockDim.x + threadIdx.x;
    if (t >= K * N) return;
    int n = t / K, k = t - n * K;
    WT[t] = __float2bfloat16(W[(long)k * N + n]);
}

// extra rows HC+2h (=W@a_src_h), HC+2h+1 (=W@a_dst_h)
__global__ void wext(const float* __restrict__ W, const float* __restrict__ a_src,
                     const float* __restrict__ a_dst, __hip_bfloat16* __restrict__ WT,
                     int K, int HC, int Hh, int C) {
    int t = blockIdx.x * blockDim.x + threadIdx.x;
    if (t >= 2 * Hh * K) return;
    int r = t / K, k = t - r * K;
    int h = r >> 1;
    const float* av = ((r & 1) ? a_dst : a_src) + h * C;
    const float* wp = W + (long)k * HC + h * C;
    float s = 0.f;
    for (int c = 0; c < C; ++c) s += av[c] * wp[c];
    WT[(long)(HC + r) * K + k] = __float2bfloat16(s);
}

// ---------------- MFMA bf16 GEMM with attention-projection epilogue ----------------
__global__ __launch_bounds__(256) void gemm_bf16(
        const __hip_bfloat16* __restrict__ A, const __hip_bfloat16* __restrict__ BT,
        __hip_bfloat16* __restrict__ Cb, float* __restrict__ Cf,
        const float* __restrict__ bias, float* __restrict__ asv, float* __restrict__ adv,
        int M, int K, int Nlog, int HC, int Hh) {
    __shared__ __align__(16) __hip_bfloat16 As[64][40];
    __shared__ __align__(16) __hip_bfloat16 Bs[64][40];
    int t = threadIdx.x;
    int wave = t >> 6, lane = t & 63;
    int wm = wave >> 1, wn = wave & 1;
    int m0 = blockIdx.y * 64, n0 = blockIdx.x * 64;
    int lrow = lane & 15, kb = lane >> 4;

    f32x4 acc[2][2] = {};
    int srow = t >> 2, scol = (t & 3) * 8;

    for (int k0 = 0; k0 < K; k0 += 32) {
        int gr = m0 + srow;
        short8v av = {};
        if (gr < M) av = *(const short8v*)(A + (long)gr * K + k0 + scol);
        int gn = n0 + srow;
        short8v bv = {};
        if (gn < Nlog) bv = *(const short8v*)(BT + (long)gn * K + k0 + scol);
        __syncthreads();
        *(short8v*)&As[srow][scol] = av;
        *(short8v*)&Bs[srow][scol] = bv;
        __syncthreads();
        short8v a0 = *(const short8v*)&As[wm * 32 + lrow][kb * 8];
        short8v a1 = *(const short8v*)&As[wm * 32 + 16 + lrow][kb * 8];
        short8v b0 = *(const short8v*)&Bs[wn * 32 + lrow][kb * 8];
        short8v b1 = *(const short8v*)&Bs[wn * 32 + 16 + lrow][kb * 8];
        acc[0][0] = __builtin_amdgcn_mfma_f32_16x16x32_bf16(a0, b0, acc[0][0], 0, 0, 0);
        acc[0][1] = __builtin_amdgcn_mfma_f32_16x16x32_bf16(a0, b1, acc[0][1], 0, 0, 0);
        acc[1][0] = __builtin_amdgcn_mfma_f32_16x16x32_bf16(a1, b0, acc[1][0], 0, 0, 0);
        acc[1][1] = __builtin_amdgcn_mfma_f32_16x16x32_bf16(a1, b1, acc[1][1], 0, 0, 0);
    }
#pragma unroll
    for (int i = 0; i < 2; ++i)
#pragma unroll
        for (int j = 0; j < 2; ++j) {
            int col = n0 + wn * 32 + j * 16 + lrow;
            if (col >= Nlog) continue;
#pragma unroll
            for (int r = 0; r < 4; ++r) {
                int row = m0 + wm * 32 + i * 16 + kb * 4 + r;
                if (row >= M) continue;
                float v = acc[i][j][r];
                if (col < HC) {
                    if (Cf) Cf[(long)row * HC + col] = v + (bias ? bias[col] : 0.f);
                    else Cb[(long)row * HC + col] = __float2bfloat16(v);
                } else {
                    int f = col - HC, h = f >> 1;
                    if (f & 1) adv[row * Hh + h] = v;
                    else       asv[row * Hh + h] = v;
                }
            }
        }
}

// ---------------- CSR build ----------------

__global__ void hist_kernel(const int* __restrict__ dst, int* __restrict__ cnt,
                            int E, int Etot) {
    int e = blockIdx.x * blockDim.x + threadIdx.x;
    if (e >= Etot) return;
    int d = (e < E) ? dst[e] : (e - E);
    atomicAdd(&cnt[d], 1);
}

__global__ void zero_int(int* __restrict__ p, int n) {
    int t = blockIdx.x * blockDim.x + threadIdx.x;
    if (t < n) p[t] = 0;
}

__global__ void scan1(const int* __restrict__ cnt, int* __restrict__ rowptr,
                      int* __restrict__ bsum, int n) {
    __shared__ int s[256];
    int i = blockIdx.x * 256 + threadIdx.x;
    int v = (i < n) ? cnt[i] : 0;
    s[threadIdx.x] = v;
    __syncthreads();
    for (int off = 1; off < 256; off <<= 1) {
        int t = (threadIdx.x >= off) ? s[threadIdx.x - off] : 0;
        __syncthreads();
        s[threadIdx.x] += t;
        __syncthreads();
    }
    if (i < n) rowptr[i] = s[threadIdx.x] - v;
    if (threadIdx.x == 255) bsum[blockIdx.x] = s[255];
}

__global__ void scan2(int* __restrict__ bsum, int nb) {
    __shared__ int s[256];
    int v = (threadIdx.x < nb) ? bsum[threadIdx.x] : 0;
    s[threadIdx.x] = v;
    __syncthreads();
    for (int off = 1; off < 256; off <<= 1) {
        int t = (threadIdx.x >= off) ? s[threadIdx.x - off] : 0;
        __syncthreads();
        s[threadIdx.x] += t;
        __syncthreads();
    }
    if (threadIdx.x < nb) bsum[threadIdx.x] = s[threadIdx.x] - v;
}

__global__ void scan3(int* __restrict__ rowptr, const int* __restrict__ bsum,
                      int* __restrict__ cnt, int n, int Etot) {
    int i = blockIdx.x * 256 + threadIdx.x;
    if (i < n) {
        rowptr[i] += bsum[blockIdx.x];
        cnt[i] = 0;
    }
    if (i == 0) rowptr[n] = Etot;
}

__global__ void fill_kernel(const int* __restrict__ src, const int* __restrict__ dst,
                            const int* __restrict__ rowptr, int* __restrict__ cursor,
                            int* __restrict__ esrc, int E, int Etot) {
    int e = blockIdx.x * blockDim.x + threadIdx.x;
    if (e >= Etot) return;
    int s = (e < E) ? src[e] : (e - E);
    int d = (e < E) ? dst[e] : (e - E);
    int pos = atomicAdd(&cursor[d], 1);
    esrc[rowptr[d] + pos] = s;
}

// ---------------- fused softmax + gather (deferred-normalization) ----------------
// alpha = exp(lg)/sum(exp(lg)): common scale cancels, so no max tracking.
// Wave 0 computes p=exp(lg) per 64-edge chunk; per-lane denominator partials,
// single butterfly at the end. Each thread gathers 8 contiguous channels (16B
// loads) over EPB edge slices with a 2-stage pipeline.
template <int HH, int C, int EPB>
__global__ void gat_gather(const int* __restrict__ rowptr, const int* __restrict__ esrc,
                           const __hip_bfloat16* __restrict__ H,
                           const float* __restrict__ asv, const float* __restrict__ adv,
                           const float* __restrict__ bias, __hip_bfloat16* __restrict__ out,
                           int act) {
    constexpr int HC  = HH * C;
    constexpr int TPE = HC / 8;
    const int d = blockIdx.x;
    const int begin = rowptr[d], end = rowptr[d + 1];
    const int t = threadIdx.x;

    __shared__ int   sSrc[64];
    __shared__ float sAl[HH][65];     // +1 pad: head rows in distinct banks
    __shared__ float sDen[HH];
    __shared__ float sPart[(EPB - 1) * TPE * 8];

    const int sub = t / TPE;
    const int tq  = t - sub * TPE;
    const int c8  = tq * 8;           // 8 contiguous channels, same head
    const int hc  = c8 / C;
    float acc[8] = {};

    float s_lane[HH];
    float adn[HH];
#pragma unroll
    for (int h = 0; h < HH; ++h) s_lane[h] = 0.f;
    if (t < 64) {
#pragma unroll
        for (int h = 0; h < HH; ++h) adn[h] = adv[d * HH + h];
    }

    for (int chunk = begin; chunk < end; chunk += 64) {
        int n = end - chunk; if (n > 64) n = 64;
        __syncthreads();                       // protect prev sSrc/sAl reads
        if (t < n) sSrc[t] = esrc[chunk + t];
        __syncthreads();

        if (t < n) {                           // wave 0 only (n <= 64)
            int s = sSrc[t];
            if (HH == 4) {
                float4 av4 = *(const float4*)(asv + s * 4);
                float vv[4] = {av4.x, av4.y, av4.z, av4.w};
#pragma unroll
                for (int h = 0; h < HH; ++h) {
                    float v = vv[h] + adn[h];
                    v = (v > 0.f) ? v : NEG_SLOPE * v;
                    float p = __expf(fminf(v, 60.f));
                    sAl[h][t] = p;
                    s_lane[h] += p;
                }
            } else {
                float v = asv[s] + adn[0];
                v = (v > 0.f) ? v : NEG_SLOPE * v;
                float p = __expf(fminf(v, 60.f));
                sAl[0][t] = p;
                s_lane[0] += p;
            }
        }
        __syncthreads();

        // gather: 2-stage pipelined over k = sub, sub+EPB, ...
        int k = sub;
        bool have = (k < n);
        int sc = 0; float pc = 0.f; short8v vc = {};
        if (have) {
            sc = sSrc[k]; pc = sAl[hc][k];
            vc = *(const short8v*)(H + (long)sc * HC + c8);
        }
        while (have) {
            int k1 = k + EPB;
            bool have1 = (k1 < n);
            int s1 = 0; float p1 = 0.f; short8v v1 = {};
            if (have1) {
                s1 = sSrc[k1]; p1 = sAl[hc][k1];
                v1 = *(const short8v*)(H + (long)s1 * HC + c8);
            }
#pragma unroll
            for (int j = 0; j < 8; ++j)
                acc[j] += pc * bfu2f((unsigned short)vc[j]);
            k = k1; pc = p1; vc = v1; have = have1;
        }
    }

    // finalize denominator: butterfly over wave 0
    if (t < 64) {
        float sl[HH];
#pragma unroll
        for (int h = 0; h < HH; ++h) {
            sl[h] = s_lane[h];
#pragma unroll
            for (int msk = 1; msk < 64; msk <<= 1)
                sl[h] += __shfl_xor(sl[h], msk);
        }
        if (t == 0) {
#pragma unroll
            for (int h = 0; h < HH; ++h) sDen[h] = sl[h] + 1e-16f;
        }
    }
    __syncthreads();

    if constexpr (EPB > 1) {
        constexpr int stride = (EPB - 1) * TPE;
        if (sub > 0) {
            int b = (sub - 1) * TPE + tq;
#pragma unroll
            for (int j = 0; j < 8; ++j) sPart[j * stride + b] = acc[j];
        }
        __syncthreads();
        if (sub == 0) {
            for (int s2 = 0; s2 < EPB - 1; ++s2) {
#pragma unroll
                for (int j = 0; j < 8; ++j) acc[j] += sPart[j * stride + s2 * TPE + tq];
            }
        }
    }
    if (sub == 0) {
        float inv = 1.0f / sDen[hc];
        short8v o;
#pragma unroll
        for (int j = 0; j < 8; ++j) {
            float r = acc[j] * inv + bias[c8 + j];
            if (act == 1) r = fmaxf(r, 0.f);
            else if (act == 2) r = tanhf(r);
            o[j] = (short)(__bfloat16_as_ushort(__float2bfloat16(r)));
        }
        *(short8v*)(out + (long)d * HC + c8) = o;
    }
}

// ---------------- launch ----------------

extern "C" void kernel_launch(void* const* d_in, const int* in_sizes, int n_in,
                              void* d_out, int out_size, void* d_ws, size_t ws_size,
                              hipStream_t stream) {
    const float* x    = (const float*)d_in[0];
    const int*   ei   = (const int*)d_in[1];
    const float* W1   = (const float*)d_in[2];
    const float* a1s  = (const float*)d_in[3];
    const float* a1d  = (const float*)d_in[4];
    const float* b1   = (const float*)d_in[5];
    const float* W2   = (const float*)d_in[6];
    const float* a2s  = (const float*)d_in[7];
    const float* a2d  = (const float*)d_in[8];
    const float* b2   = (const float*)d_in[9];
    const float* W3   = (const float*)d_in[10];
    const float* a3s  = (const float*)d_in[11];
    const float* a3d  = (const float*)d_in[12];
    const float* b3   = (const float*)d_in[13];
    const float* Wc   = (const float*)d_in[14];
    const float* bc   = (const float*)d_in[15];

    const int F0 = 256;
    int N = in_sizes[0] / F0;          // 50000
    int E = in_sizes[1] / 2;           // 800000
    int Etot = E + N;
    const int* srcI = ei;
    const int* dstI = ei + E;

    // ---- workspace carve ----
    char* p = (char*)d_ws;
    auto alloc = [&](size_t bytes) { void* r = p; p += (bytes + 255) & ~(size_t)255; return r; };
    __hip_bfloat16* xb  = (__hip_bfloat16*)alloc((size_t)N * 256 * 2);
    __hip_bfloat16* Hb  = (__hip_bfloat16*)alloc((size_t)N * 384 * 2);
    __hip_bfloat16* O1  = (__hip_bfloat16*)alloc((size_t)N * 384 * 2);
    __hip_bfloat16* O2  = (__hip_bfloat16*)alloc((size_t)N * 128 * 2);
    __hip_bfloat16* O3  = (__hip_bfloat16*)alloc((size_t)N * 64 * 2);
    __hip_bfloat16* W1T = (__hip_bfloat16*)alloc((size_t)(384 + 8) * 256 * 2);
    __hip_bfloat16* W2T = (__hip_bfloat16*)alloc((size_t)(128 + 2) * 384 * 2);
    __hip_bfloat16* W3T = (__hip_bfloat16*)alloc((size_t)(64 + 2) * 128 * 2);
    __hip_bfloat16* WcT = (__hip_bfloat16*)alloc((size_t)40 * 64 * 2);
    float* as_  = (float*)alloc((size_t)N * 4 * 4);
    float* ad_  = (float*)alloc((size_t)N * 4 * 4);
    int* rowptr = (int*)alloc((size_t)(N + 1) * 4);
    int* cnt    = (int*)alloc((size_t)N * 4);
    int* esrc   = (int*)alloc((size_t)Etot * 4);
    int* bsum   = (int*)alloc(256 * 4);

    // ---- input casts / weight prep ----
    long nx = (long)N * 256;
    cast_bf16_4<<<(int)((nx / 4 + 255) / 256), 256, 0, stream>>>(x, xb, nx);
    wtrans<<<(256 * 384 + 255) / 256, 256, 0, stream>>>(W1, W1T, 256, 384);
    wtrans<<<(384 * 128 + 255) / 256, 256, 0, stream>>>(W2, W2T, 384, 128);
    wtrans<<<(128 * 64 + 255) / 256, 256, 0, stream>>>(W3, W3T, 128, 64);
    wtrans<<<(64 * 40 + 255) / 256, 256, 0, stream>>>(Wc, WcT, 64, 40);
    wext<<<(8 * 256 + 255) / 256, 256, 0, stream>>>(W1, a1s, a1d, W1T, 256, 384, 4, 96);
    wext<<<(2 * 384 + 255) / 256, 256, 0, stream>>>(W2, a2s, a2d, W2T, 384, 128, 1, 128);
    wext<<<(2 * 128 + 255) / 256, 256, 0, stream>>>(W3, a3s, a3d, W3T, 128, 64, 1, 64);

    // ---- CSR build ----
    int nb = (N + 255) / 256;
    zero_int<<<nb, 256, 0, stream>>>(cnt, N);
    hist_kernel<<<(Etot + 255) / 256, 256, 0, stream>>>(dstI, cnt, E, Etot);
    scan1<<<nb, 256, 0, stream>>>(cnt, rowptr, bsum, N);
    scan2<<<1, 256, 0, stream>>>(bsum, nb);
    scan3<<<nb, 256, 0, stream>>>(rowptr, bsum, cnt, N, Etot);
    fill_kernel<<<(Etot + 255) / 256, 256, 0, stream>>>(srcI, dstI, rowptr, cnt, esrc, E, Etot);

    auto run_gemm = [&](const __hip_bfloat16* X, int Fin, const __hip_bfloat16* WT,
                        int Hh, int C) {
        int HC = Hh * C;
        int Nlog = HC + 2 * Hh;
        dim3 gg((Nlog + 63) / 64, (N + 63) / 64);
        gemm_bf16<<<gg, 256, 0, stream>>>(X, WT, Hb, nullptr, nullptr, as_, ad_,
                                          N, Fin, Nlog, HC, Hh);
    };

    // Layer 1: 256 -> 4x96, relu   (TPE=48, EPB=4 -> block 192)
    run_gemm(xb, 256, W1T, 4, 96);
    gat_gather<4, 96, 4><<<N, 192, 0, stream>>>(rowptr, esrc, Hb, as_, ad_, b1, O1, 1);
    // Layer 2: 384 -> 1x128, tanh  (TPE=16, EPB=4 -> block 64)
    run_gemm(O1, 384, W2T, 1, 128);
    gat_gather<1, 128, 4><<<N, 64, 0, stream>>>(rowptr, esrc, Hb, as_, ad_, b2, O2, 2);
    // Layer 3: 128 -> 1x64, tanh   (TPE=8, EPB=8 -> block 64)
    run_gemm(O2, 128, W3T, 1, 64);
    gat_gather<1, 64, 8><<<N, 64, 0, stream>>>(rowptr, esrc, Hb, as_, ad_, b3, O3, 2);

    // Classifier: out = O3 @ Wc + bc   [N,40] f32
    float* out = (float*)d_out;
    dim3 gg((40 + 63) / 64, (N + 63) / 64);
    gemm_bf16<<<gg, 256, 0, stream>>>(O3, WcT, nullptr, out, bc, as_, ad_,
                                      N, 64, 40, 40, 0);
}

// Round 7
// 396.101 us; speedup vs baseline: 6.1955x; 1.0922x over previous
//
#include <hip/hip_runtime.h>
#include <hip/hip_bf16.h>
#include <math.h>

#define NEG_SLOPE 0.2f

typedef __attribute__((ext_vector_type(8))) short short8v;   // 8 bf16
typedef __attribute__((ext_vector_type(4))) float f32x4;

__device__ __forceinline__ float bfu2f(unsigned short u) {
    return __uint_as_float((unsigned)u << 16);
}

// ---------------- casts / weight prep ----------------

__global__ void cast_bf16_4(const float* __restrict__ in, __hip_bfloat16* __restrict__ out,
                            long n) {
    long i = ((long)blockIdx.x * blockDim.x + threadIdx.x) * 4;
    if (i >= n) return;
    float4 v = *(const float4*)(in + i);
    __hip_bfloat162* o = (__hip_bfloat162*)(out + i);
    o[0] = __hip_bfloat162{__float2bfloat16(v.x), __float2bfloat16(v.y)};
    o[1] = __hip_bfloat162{__float2bfloat16(v.z), __float2bfloat16(v.w)};
}

__device__ __forceinline__ void trans1(const float* __restrict__ W,
                                       __hip_bfloat16* __restrict__ WT,
                                       int K, int N, int t) {
    int n = t / K, k = t - n * K;
    WT[t] = __float2bfloat16(W[(long)k * N + n]);
}

__device__ __forceinline__ void wext1(const float* __restrict__ W,
                                      const float* __restrict__ as,
                                      const float* __restrict__ ad,
                                      __hip_bfloat16* __restrict__ WT,
                                      int K, int HC, int C, int t) {
    int r = t / K, k = t - r * K;
    int h = r >> 1;
    const float* av = ((r & 1) ? ad : as) + h * C;
    const float* wp = W + (long)k * HC + h * C;
    float s = 0.f;
    for (int c = 0; c < C; ++c) s += av[c] * wp[c];
    WT[(long)(HC + r) * K + k] = __float2bfloat16(s);
}

// All weight transposes + attention projections in one launch.
// Segments: [0,98304) W1T | [98304,147456) W2T | [147456,155648) W3T |
// [155648,158208) WcT | [158208,160256) wext1 | [160256,161024) wext2 |
// [161024,161280) wext3
__global__ void prep_weights(const float* __restrict__ W1, const float* __restrict__ a1s,
                             const float* __restrict__ a1d, const float* __restrict__ W2,
                             const float* __restrict__ a2s, const float* __restrict__ a2d,
                             const float* __restrict__ W3, const float* __restrict__ a3s,
                             const float* __restrict__ a3d, const float* __restrict__ Wc,
                             __hip_bfloat16* __restrict__ W1T, __hip_bfloat16* __restrict__ W2T,
                             __hip_bfloat16* __restrict__ W3T, __hip_bfloat16* __restrict__ WcT) {
    int t = blockIdx.x * blockDim.x + threadIdx.x;
    if (t < 98304)       trans1(W1, W1T, 256, 384, t);
    else if (t < 147456) trans1(W2, W2T, 384, 128, t - 98304);
    else if (t < 155648) trans1(W3, W3T, 128, 64, t - 147456);
    else if (t < 158208) trans1(Wc, WcT, 64, 40, t - 155648);
    else if (t < 160256) wext1(W1, a1s, a1d, W1T, 256, 384, 96, t - 158208);
    else if (t < 161024) wext1(W2, a2s, a2d, W2T, 384, 128, 128, t - 160256);
    else if (t < 161280) wext1(W3, a3s, a3d, W3T, 128, 64, 64, t - 161024);
}

// ---------------- MFMA bf16 GEMM (128x64 tile) with attention epilogue ----------------
// C[M, 0..HC-1] = A[M,K] @ BT[0..HC-1,K]^T ; cols >= HC -> asv/adv (f32)
__global__ __launch_bounds__(256) void gemm_bf16(
        const __hip_bfloat16* __restrict__ A, const __hip_bfloat16* __restrict__ BT,
        __hip_bfloat16* __restrict__ Cb, float* __restrict__ Cf,
        const float* __restrict__ bias, float* __restrict__ asv, float* __restrict__ adv,
        int M, int K, int Nlog, int HC, int Hh) {
    __shared__ __align__(16) __hip_bfloat16 As[128][40];   // +8 pad: 2-way reads (free)
    __shared__ __align__(16) __hip_bfloat16 Bs[64][40];
    int t = threadIdx.x;
    int wave = t >> 6, lane = t & 63;
    int wm = wave >> 1, wn = wave & 1;              // 2x2 waves: wave tile 64x32
    int m0 = blockIdx.y * 128, n0 = blockIdx.x * 64;
    int lrow = lane & 15, kb = lane >> 4;

    f32x4 acc[4][2] = {};
    int arow = t >> 1, acol = (t & 1) * 16;         // A: 2 threads/row, 32B each
    int brow = t >> 2, bcol = (t & 3) * 8;          // B: 4 threads/row, 16B each

    for (int k0 = 0; k0 < K; k0 += 32) {
        int gr = m0 + arow;
        short8v av0 = {}, av1 = {};
        if (gr < M) {
            const __hip_bfloat16* ap = A + (long)gr * K + k0 + acol;
            av0 = *(const short8v*)ap;
            av1 = *(const short8v*)(ap + 8);
        }
        int gn = n0 + brow;
        short8v bv = {};
        if (gn < Nlog) bv = *(const short8v*)(BT + (long)gn * K + k0 + bcol);
        __syncthreads();
        *(short8v*)&As[arow][acol] = av0;
        *(short8v*)&As[arow][acol + 8] = av1;
        *(short8v*)&Bs[brow][bcol] = bv;
        __syncthreads();
        short8v b0 = *(const short8v*)&Bs[wn * 32 + lrow][kb * 8];
        short8v b1 = *(const short8v*)&Bs[wn * 32 + 16 + lrow][kb * 8];
#pragma unroll
        for (int i = 0; i < 4; ++i) {
            short8v a = *(const short8v*)&As[wm * 64 + i * 16 + lrow][kb * 8];
            acc[i][0] = __builtin_amdgcn_mfma_f32_16x16x32_bf16(a, b0, acc[i][0], 0, 0, 0);
            acc[i][1] = __builtin_amdgcn_mfma_f32_16x16x32_bf16(a, b1, acc[i][1], 0, 0, 0);
        }
    }
#pragma unroll
    for (int i = 0; i < 4; ++i)
#pragma unroll
        for (int j = 0; j < 2; ++j) {
            int col = n0 + wn * 32 + j * 16 + lrow;
            if (col >= Nlog) continue;
#pragma unroll
            for (int r = 0; r < 4; ++r) {
                int row = m0 + wm * 64 + i * 16 + kb * 4 + r;
                if (row >= M) continue;
                float v = acc[i][j][r];
                if (col < HC) {
                    if (Cf) Cf[(long)row * HC + col] = v + (bias ? bias[col] : 0.f);
                    else Cb[(long)row * HC + col] = __float2bfloat16(v);
                } else {
                    int f = col - HC, h = f >> 1;
                    if (f & 1) adv[row * Hh + h] = v;
                    else       asv[row * Hh + h] = v;
                }
            }
        }
}

// ---------------- CSR build ----------------

__global__ void hist_kernel(const int* __restrict__ dst, int* __restrict__ cnt,
                            int E, int Etot) {
    int e = blockIdx.x * blockDim.x + threadIdx.x;
    if (e >= Etot) return;
    int d = (e < E) ? dst[e] : (e - E);
    atomicAdd(&cnt[d], 1);
}

__global__ void zero_int(int* __restrict__ p, int n) {
    int t = blockIdx.x * blockDim.x + threadIdx.x;
    if (t < n) p[t] = 0;
}

__global__ void scan1(const int* __restrict__ cnt, int* __restrict__ rowptr,
                      int* __restrict__ bsum, int n) {
    __shared__ int s[256];
    int i = blockIdx.x * 256 + threadIdx.x;
    int v = (i < n) ? cnt[i] : 0;
    s[threadIdx.x] = v;
    __syncthreads();
    for (int off = 1; off < 256; off <<= 1) {
        int t = (threadIdx.x >= off) ? s[threadIdx.x - off] : 0;
        __syncthreads();
        s[threadIdx.x] += t;
        __syncthreads();
    }
    if (i < n) rowptr[i] = s[threadIdx.x] - v;
    if (threadIdx.x == 255) bsum[blockIdx.x] = s[255];
}

__global__ void scan2(int* __restrict__ bsum, int nb) {
    __shared__ int s[256];
    int v = (threadIdx.x < nb) ? bsum[threadIdx.x] : 0;
    s[threadIdx.x] = v;
    __syncthreads();
    for (int off = 1; off < 256; off <<= 1) {
        int t = (threadIdx.x >= off) ? s[threadIdx.x - off] : 0;
        __syncthreads();
        s[threadIdx.x] += t;
        __syncthreads();
    }
    if (threadIdx.x < nb) bsum[threadIdx.x] = s[threadIdx.x] - v;
}

__global__ void scan3(int* __restrict__ rowptr, const int* __restrict__ bsum,
                      int* __restrict__ cnt, int n, int Etot) {
    int i = blockIdx.x * 256 + threadIdx.x;
    if (i < n) {
        rowptr[i] += bsum[blockIdx.x];
        cnt[i] = 0;
    }
    if (i == 0) rowptr[n] = Etot;
}

__global__ void fill_kernel(const int* __restrict__ src, const int* __restrict__ dst,
                            const int* __restrict__ rowptr, int* __restrict__ cursor,
                            int* __restrict__ esrc, int E, int Etot) {
    int e = blockIdx.x * blockDim.x + threadIdx.x;
    if (e >= Etot) return;
    int s = (e < E) ? src[e] : (e - E);
    int d = (e < E) ? dst[e] : (e - E);
    int pos = atomicAdd(&cursor[d], 1);
    esrc[rowptr[d] + pos] = s;
}

// ---------------- fused softmax + gather (deferred-normalization) ----------------
template <int HH, int C, int EPB>
__global__ void gat_gather(const int* __restrict__ rowptr, const int* __restrict__ esrc,
                           const __hip_bfloat16* __restrict__ H,
                           const float* __restrict__ asv, const float* __restrict__ adv,
                           const float* __restrict__ bias, __hip_bfloat16* __restrict__ out,
                           int act) {
    constexpr int HC  = HH * C;
    constexpr int TPE = HC / 8;
    const int d = blockIdx.x;
    const int begin = rowptr[d], end = rowptr[d + 1];
    const int t = threadIdx.x;

    __shared__ int   sSrc[64];
    __shared__ float sAl[HH][65];     // +1 pad: head rows in distinct banks
    __shared__ float sDen[HH];
    __shared__ float sPart[(EPB - 1) * TPE * 8];

    const int sub = t / TPE;
    const int tq  = t - sub * TPE;
    const int c8  = tq * 8;           // 8 contiguous channels, same head
    const int hc  = c8 / C;
    float acc[8] = {};

    float s_lane[HH];
    float adn[HH];
#pragma unroll
    for (int h = 0; h < HH; ++h) s_lane[h] = 0.f;
    if (t < 64) {
#pragma unroll
        for (int h = 0; h < HH; ++h) adn[h] = adv[d * HH + h];
    }

    for (int chunk = begin; chunk < end; chunk += 64) {
        int n = end - chunk; if (n > 64) n = 64;
        __syncthreads();                       // protect prev sSrc/sAl reads
        if (t < n) sSrc[t] = esrc[chunk + t];
        __syncthreads();

        if (t < n) {                           // wave 0 only (n <= 64)
            int s = sSrc[t];
            if (HH == 4) {
                float4 av4 = *(const float4*)(asv + s * 4);
                float vv[4] = {av4.x, av4.y, av4.z, av4.w};
#pragma unroll
                for (int h = 0; h < HH; ++h) {
                    float v = vv[h] + adn[h];
                    v = (v > 0.f) ? v : NEG_SLOPE * v;
                    float p = __expf(fminf(v, 60.f));
                    sAl[h][t] = p;
                    s_lane[h] += p;
                }
            } else {
                float v = asv[s] + adn[0];
                v = (v > 0.f) ? v : NEG_SLOPE * v;
                float p = __expf(fminf(v, 60.f));
                sAl[0][t] = p;
                s_lane[0] += p;
            }
        }
        __syncthreads();

        // gather: 2-stage pipelined over k = sub, sub+EPB, ...
        int k = sub;
        bool have = (k < n);
        float pc = 0.f; short8v vc = {};
        if (have) {
            pc = sAl[hc][k];
            vc = *(const short8v*)(H + (long)sSrc[k] * HC + c8);
        }
        while (have) {
            int k1 = k + EPB;
            bool have1 = (k1 < n);
            float p1 = 0.f; short8v v1 = {};
            if (have1) {
                p1 = sAl[hc][k1];
                v1 = *(const short8v*)(H + (long)sSrc[k1] * HC + c8);
            }
#pragma unroll
            for (int j = 0; j < 8; ++j)
                acc[j] += pc * bfu2f((unsigned short)vc[j]);
            k = k1; pc = p1; vc = v1; have = have1;
        }
    }

    // finalize denominator: butterfly over wave 0
    if (t < 64) {
        float sl[HH];
#pragma unroll
        for (int h = 0; h < HH; ++h) {
            sl[h] = s_lane[h];
#pragma unroll
            for (int msk = 1; msk < 64; msk <<= 1)
                sl[h] += __shfl_xor(sl[h], msk);
        }
        if (t == 0) {
#pragma unroll
            for (int h = 0; h < HH; ++h) sDen[h] = sl[h] + 1e-16f;
        }
    }
    __syncthreads();

    if constexpr (EPB > 1) {
        constexpr int stride = (EPB - 1) * TPE;
        if (sub > 0) {
            int b = (sub - 1) * TPE + tq;
#pragma unroll
            for (int j = 0; j < 8; ++j) sPart[j * stride + b] = acc[j];
        }
        __syncthreads();
        if (sub == 0) {
            for (int s2 = 0; s2 < EPB - 1; ++s2) {
#pragma unroll
                for (int j = 0; j < 8; ++j) acc[j] += sPart[j * stride + s2 * TPE + tq];
            }
        }
    }
    if (sub == 0) {
        float inv = 1.0f / sDen[hc];
        short8v o;
#pragma unroll
        for (int j = 0; j < 8; ++j) {
            float r = acc[j] * inv + bias[c8 + j];
            if (act == 1) r = fmaxf(r, 0.f);
            else if (act == 2) r = tanhf(r);
            o[j] = (short)(__bfloat16_as_ushort(__float2bfloat16(r)));
        }
        *(short8v*)(out + (long)d * HC + c8) = o;
    }
}

// ---------------- launch ----------------

extern "C" void kernel_launch(void* const* d_in, const int* in_sizes, int n_in,
                              void* d_out, int out_size, void* d_ws, size_t ws_size,
                              hipStream_t stream) {
    const float* x    = (const float*)d_in[0];
    const int*   ei   = (const int*)d_in[1];
    const float* W1   = (const float*)d_in[2];
    const float* a1s  = (const float*)d_in[3];
    const float* a1d  = (const float*)d_in[4];
    const float* b1   = (const float*)d_in[5];
    const float* W2   = (const float*)d_in[6];
    const float* a2s  = (const float*)d_in[7];
    const float* a2d  = (const float*)d_in[8];
    const float* b2   = (const float*)d_in[9];
    const float* W3   = (const float*)d_in[10];
    const float* a3s  = (const float*)d_in[11];
    const float* a3d  = (const float*)d_in[12];
    const float* b3   = (const float*)d_in[13];
    const float* Wc   = (const float*)d_in[14];
    const float* bc   = (const float*)d_in[15];

    const int F0 = 256;
    int N = in_sizes[0] / F0;          // 50000
    int E = in_sizes[1] / 2;           // 800000
    int Etot = E + N;
    const int* srcI = ei;
    const int* dstI = ei + E;

    // ---- workspace carve ----
    char* p = (char*)d_ws;
    auto alloc = [&](size_t bytes) { void* r = p; p += (bytes + 255) & ~(size_t)255; return r; };
    __hip_bfloat16* xb  = (__hip_bfloat16*)alloc((size_t)N * 256 * 2);
    __hip_bfloat16* Hb  = (__hip_bfloat16*)alloc((size_t)N * 384 * 2);
    __hip_bfloat16* O1  = (__hip_bfloat16*)alloc((size_t)N * 384 * 2);
    __hip_bfloat16* O2  = (__hip_bfloat16*)alloc((size_t)N * 128 * 2);
    __hip_bfloat16* O3  = (__hip_bfloat16*)alloc((size_t)N * 64 * 2);
    __hip_bfloat16* W1T = (__hip_bfloat16*)alloc((size_t)(384 + 8) * 256 * 2);
    __hip_bfloat16* W2T = (__hip_bfloat16*)alloc((size_t)(128 + 2) * 384 * 2);
    __hip_bfloat16* W3T = (__hip_bfloat16*)alloc((size_t)(64 + 2) * 128 * 2);
    __hip_bfloat16* WcT = (__hip_bfloat16*)alloc((size_t)40 * 64 * 2);
    float* as_  = (float*)alloc((size_t)N * 4 * 4);
    float* ad_  = (float*)alloc((size_t)N * 4 * 4);
    int* rowptr = (int*)alloc((size_t)(N + 1) * 4);
    int* cnt    = (int*)alloc((size_t)N * 4);
    int* esrc   = (int*)alloc((size_t)Etot * 4);
    int* bsum   = (int*)alloc(256 * 4);

    // ---- input cast + merged weight prep ----
    long nx = (long)N * 256;
    cast_bf16_4<<<(int)((nx / 4 + 255) / 256), 256, 0, stream>>>(x, xb, nx);
    prep_weights<<<(161280 + 255) / 256, 256, 0, stream>>>(
        W1, a1s, a1d, W2, a2s, a2d, W3, a3s, a3d, Wc, W1T, W2T, W3T, WcT);

    // ---- CSR build ----
    int nb = (N + 255) / 256;
    zero_int<<<nb, 256, 0, stream>>>(cnt, N);
    hist_kernel<<<(Etot + 255) / 256, 256, 0, stream>>>(dstI, cnt, E, Etot);
    scan1<<<nb, 256, 0, stream>>>(cnt, rowptr, bsum, N);
    scan2<<<1, 256, 0, stream>>>(bsum, nb);
    scan3<<<nb, 256, 0, stream>>>(rowptr, bsum, cnt, N, Etot);
    fill_kernel<<<(Etot + 255) / 256, 256, 0, stream>>>(srcI, dstI, rowptr, cnt, esrc, E, Etot);

    auto run_gemm = [&](const __hip_bfloat16* X, int Fin, const __hip_bfloat16* WT,
                        int Hh, int C) {
        int HC = Hh * C;
        int Nlog = HC + 2 * Hh;
        dim3 gg((Nlog + 63) / 64, (N + 127) / 128);
        gemm_bf16<<<gg, 256, 0, stream>>>(X, WT, Hb, nullptr, nullptr, as_, ad_,
                                          N, Fin, Nlog, HC, Hh);
    };

    // Layer 1: 256 -> 4x96, relu   (TPE=48, EPB=4 -> block 192)
    run_gemm(xb, 256, W1T, 4, 96);
    gat_gather<4, 96, 4><<<N, 192, 0, stream>>>(rowptr, esrc, Hb, as_, ad_, b1, O1, 1);
    // Layer 2: 384 -> 1x128, tanh  (TPE=16, EPB=4 -> block 64)
    run_gemm(O1, 384, W2T, 1, 128);
    gat_gather<1, 128, 4><<<N, 64, 0, stream>>>(rowptr, esrc, Hb, as_, ad_, b2, O2, 2);
    // Layer 3: 128 -> 1x64, tanh   (TPE=8, EPB=8 -> block 64)
    run_gemm(O2, 128, W3T, 1, 64);
    gat_gather<1, 64, 8><<<N, 64, 0, stream>>>(rowptr, esrc, Hb, as_, ad_, b3, O3, 2);

    // Classifier: out = O3 @ Wc + bc   [N,40] f32
    float* out = (float*)d_out;
    dim3 gg((40 + 63) / 64, (N + 127) / 128);
    gemm_bf16<<<gg, 256, 0, stream>>>(O3, WcT, nullptr, out, bc, as_, ad_,
                                      N, 64, 40, 40, 0);
}

// Round 8
// 372.021 us; speedup vs baseline: 6.5965x; 1.0647x over previous
//
#include <hip/hip_runtime.h>
#include <hip/hip_bf16.h>
#include <math.h>

#define NEG_SLOPE 0.2f

typedef __attribute__((ext_vector_type(8))) short short8v;   // 8 bf16
typedef __attribute__((ext_vector_type(4))) float f32x4;

__device__ __forceinline__ float bfu2f(unsigned short u) {
    return __uint_as_float((unsigned)u << 16);
}

// ---------------- merged prep: x cast + weight transposes + projections + cnt zero ----

__device__ __forceinline__ void trans1(const float* __restrict__ W,
                                       __hip_bfloat16* __restrict__ WT,
                                       int K, int N, int t) {
    int n = t / K, k = t - n * K;
    WT[t] = __float2bfloat16(W[(long)k * N + n]);
}

__device__ __forceinline__ void wext1(const float* __restrict__ W,
                                      const float* __restrict__ as,
                                      const float* __restrict__ ad,
                                      __hip_bfloat16* __restrict__ WT,
                                      int K, int HC, int C, int t) {
    int r = t / K, k = t - r * K;
    int h = r >> 1;
    const float* av = ((r & 1) ? ad : as) + h * C;
    const float* wp = W + (long)k * HC + h * C;
    float s = 0.f;
    for (int c = 0; c < C; ++c) s += av[c] * wp[c];
    WT[(long)(HC + r) * K + k] = __float2bfloat16(s);
}

// Segments (after nx4 cast threads): W1T 98304 | W2T 49152 | W3T 8192 | WcT 2560 |
// wext1 2048 | wext2 768 | wext3 256 | cnt N
__global__ void prep_all(const float* __restrict__ x, __hip_bfloat16* __restrict__ xb,
                         long nx4,
                         const float* __restrict__ W1, const float* __restrict__ a1s,
                         const float* __restrict__ a1d, const float* __restrict__ W2,
                         const float* __restrict__ a2s, const float* __restrict__ a2d,
                         const float* __restrict__ W3, const float* __restrict__ a3s,
                         const float* __restrict__ a3d, const float* __restrict__ Wc,
                         __hip_bfloat16* __restrict__ W1T, __hip_bfloat16* __restrict__ W2T,
                         __hip_bfloat16* __restrict__ W3T, __hip_bfloat16* __restrict__ WcT,
                         int* __restrict__ cnt, int N) {
    long t = (long)blockIdx.x * blockDim.x + threadIdx.x;
    if (t < nx4) {
        long i = t * 4;
        float4 v = *(const float4*)(x + i);
        __hip_bfloat162* o = (__hip_bfloat162*)(xb + i);
        o[0] = __hip_bfloat162{__float2bfloat16(v.x), __float2bfloat16(v.y)};
        o[1] = __hip_bfloat162{__float2bfloat16(v.z), __float2bfloat16(v.w)};
        return;
    }
    int u = (int)(t - nx4);
    if (u < 98304)       trans1(W1, W1T, 256, 384, u);
    else if (u < 147456) trans1(W2, W2T, 384, 128, u - 98304);
    else if (u < 155648) trans1(W3, W3T, 128, 64, u - 147456);
    else if (u < 158208) trans1(Wc, WcT, 64, 40, u - 155648);
    else if (u < 160256) wext1(W1, a1s, a1d, W1T, 256, 384, 96, u - 158208);
    else if (u < 161024) wext1(W2, a2s, a2d, W2T, 384, 128, 128, u - 160256);
    else if (u < 161280) wext1(W3, a3s, a3d, W3T, 128, 64, 64, u - 161024);
    else { int i = u - 161280; if (i < N) cnt[i] = 0; }
}

// ---------------- MFMA bf16 GEMM (128x64 tile) with attention epilogue ----------------
__global__ __launch_bounds__(256) void gemm_bf16(
        const __hip_bfloat16* __restrict__ A, const __hip_bfloat16* __restrict__ BT,
        __hip_bfloat16* __restrict__ Cb, float* __restrict__ Cf,
        const float* __restrict__ bias, float* __restrict__ asv, float* __restrict__ adv,
        int M, int K, int Nlog, int HC, int Hh) {
    __shared__ __align__(16) __hip_bfloat16 As[128][40];   // +8 pad: 2-way reads (free)
    __shared__ __align__(16) __hip_bfloat16 Bs[64][40];
    int t = threadIdx.x;
    int wave = t >> 6, lane = t & 63;
    int wm = wave >> 1, wn = wave & 1;              // 2x2 waves: wave tile 64x32
    int m0 = blockIdx.y * 128, n0 = blockIdx.x * 64;
    int lrow = lane & 15, kb = lane >> 4;

    f32x4 acc[4][2] = {};
    int arow = t >> 1, acol = (t & 1) * 16;
    int brow = t >> 2, bcol = (t & 3) * 8;

    for (int k0 = 0; k0 < K; k0 += 32) {
        int gr = m0 + arow;
        short8v av0 = {}, av1 = {};
        if (gr < M) {
            const __hip_bfloat16* ap = A + (long)gr * K + k0 + acol;
            av0 = *(const short8v*)ap;
            av1 = *(const short8v*)(ap + 8);
        }
        int gn = n0 + brow;
        short8v bv = {};
        if (gn < Nlog) bv = *(const short8v*)(BT + (long)gn * K + k0 + bcol);
        __syncthreads();
        *(short8v*)&As[arow][acol] = av0;
        *(short8v*)&As[arow][acol + 8] = av1;
        *(short8v*)&Bs[brow][bcol] = bv;
        __syncthreads();
        short8v b0 = *(const short8v*)&Bs[wn * 32 + lrow][kb * 8];
        short8v b1 = *(const short8v*)&Bs[wn * 32 + 16 + lrow][kb * 8];
#pragma unroll
        for (int i = 0; i < 4; ++i) {
            short8v a = *(const short8v*)&As[wm * 64 + i * 16 + lrow][kb * 8];
            acc[i][0] = __builtin_amdgcn_mfma_f32_16x16x32_bf16(a, b0, acc[i][0], 0, 0, 0);
            acc[i][1] = __builtin_amdgcn_mfma_f32_16x16x32_bf16(a, b1, acc[i][1], 0, 0, 0);
        }
    }
#pragma unroll
    for (int i = 0; i < 4; ++i)
#pragma unroll
        for (int j = 0; j < 2; ++j) {
            int col = n0 + wn * 32 + j * 16 + lrow;
            if (col >= Nlog) continue;
#pragma unroll
            for (int r = 0; r < 4; ++r) {
                int row = m0 + wm * 64 + i * 16 + kb * 4 + r;
                if (row >= M) continue;
                float v = acc[i][j][r];
                if (col < HC) {
                    if (Cf) Cf[(long)row * HC + col] = v + (bias ? bias[col] : 0.f);
                    else Cb[(long)row * HC + col] = __float2bfloat16(v);
                } else {
                    int f = col - HC, h = f >> 1;
                    if (f & 1) adv[row * Hh + h] = v;
                    else       asv[row * Hh + h] = v;
                }
            }
        }
}

// ---------------- CSR build ----------------

__global__ void hist_kernel(const int* __restrict__ dst, int* __restrict__ cnt,
                            int E, int Etot) {
    int e = blockIdx.x * blockDim.x + threadIdx.x;
    if (e >= Etot) return;
    int d = (e < E) ? dst[e] : (e - E);
    atomicAdd(&cnt[d], 1);
}

__global__ void scan1(const int* __restrict__ cnt, int* __restrict__ rowptr,
                      int* __restrict__ bsum, int n) {
    __shared__ int s[256];
    int i = blockIdx.x * 256 + threadIdx.x;
    int v = (i < n) ? cnt[i] : 0;
    s[threadIdx.x] = v;
    __syncthreads();
    for (int off = 1; off < 256; off <<= 1) {
        int t = (threadIdx.x >= off) ? s[threadIdx.x - off] : 0;
        __syncthreads();
        s[threadIdx.x] += t;
        __syncthreads();
    }
    if (i < n) rowptr[i] = s[threadIdx.x] - v;
    if (threadIdx.x == 255) bsum[blockIdx.x] = s[255];
}

__global__ void scan2(int* __restrict__ bsum, int nb) {
    __shared__ int s[256];
    int v = (threadIdx.x < nb) ? bsum[threadIdx.x] : 0;
    s[threadIdx.x] = v;
    __syncthreads();
    for (int off = 1; off < 256; off <<= 1) {
        int t = (threadIdx.x >= off) ? s[threadIdx.x - off] : 0;
        __syncthreads();
        s[threadIdx.x] += t;
        __syncthreads();
    }
    if (threadIdx.x < nb) bsum[threadIdx.x] = s[threadIdx.x] - v;
}

__global__ void scan3(int* __restrict__ rowptr, const int* __restrict__ bsum,
                      int* __restrict__ cnt, int n, int Etot) {
    int i = blockIdx.x * 256 + threadIdx.x;
    if (i < n) {
        rowptr[i] += bsum[blockIdx.x];
        cnt[i] = 0;
    }
    if (i == 0) rowptr[n] = Etot;
}

__global__ void fill_kernel(const int* __restrict__ src, const int* __restrict__ dst,
                            const int* __restrict__ rowptr, int* __restrict__ cursor,
                            int* __restrict__ esrc, int E, int Etot) {
    int e = blockIdx.x * blockDim.x + threadIdx.x;
    if (e >= Etot) return;
    int s = (e < E) ? src[e] : (e - E);
    int d = (e < E) ? dst[e] : (e - E);
    int pos = atomicAdd(&cursor[d], 1);
    esrc[rowptr[d] + pos] = s;
}

// ---------------- wave-per-node fused softmax + gather ----------------
// One 64-lane wave per dst node; 4 independent nodes per 256-thread block.
// No __syncthreads: softmax state is exchanged via per-wave LDS slices
// (same-wave DS ordering + lgkmcnt suffice). Deferred normalization (no max;
// exp clamped at 60). Gather: TPE=HC/8 lanes/edge, EPW edges in parallel.
template <int HH, int C>
__global__ __launch_bounds__(256) void gat_gather_wave(
        const int* __restrict__ rowptr, const int* __restrict__ esrc,
        const __hip_bfloat16* __restrict__ H,
        const float* __restrict__ asv, const float* __restrict__ adv,
        const float* __restrict__ bias, __hip_bfloat16* __restrict__ out,
        int act, int N) {
    constexpr int HC  = HH * C;
    constexpr int TPE = HC / 8;
    constexpr int EPW = (64 / TPE) < 1 ? 1 : ((64 / TPE) > 8 ? 8 : (64 / TPE));
    constexpr int WPB = 4;
    const int wid  = threadIdx.x >> 6;
    const int lane = threadIdx.x & 63;
    const int d = blockIdx.x * WPB + wid;
    if (d >= N) return;

    __shared__ float sAlA[WPB][HH][72];
    __shared__ int   sSrcA[WPB][64];
    float (*sAl)[72] = sAlA[wid];
    int* sSrc = sSrcA[wid];

    const int begin = rowptr[d], end = rowptr[d + 1];
    float adn[HH];
#pragma unroll
    for (int h = 0; h < HH; ++h) adn[h] = adv[d * HH + h];

    const bool act_g = (lane < TPE * EPW);
    const int g  = act_g ? (lane / TPE) : 0;
    const int tq = lane % TPE;
    const int c8 = tq * 8;
    const int hc = c8 / C;
    float acc[8] = {};
    float s_lane[HH];
#pragma unroll
    for (int h = 0; h < HH; ++h) s_lane[h] = 0.f;

    for (int chunk = begin; chunk < end; chunk += 64) {
        int n = end - chunk; if (n > 64) n = 64;
        if (lane < n) {
            int s = esrc[chunk + lane];
            sSrc[lane] = s;
            if (HH == 4) {
                float4 a4 = *(const float4*)(asv + s * 4);
                float vv[4] = {a4.x, a4.y, a4.z, a4.w};
#pragma unroll
                for (int h = 0; h < 4; ++h) {
                    float v = vv[h] + adn[h];
                    v = (v > 0.f) ? v : NEG_SLOPE * v;
                    float p = __expf(fminf(v, 60.f));
                    sAl[h][lane] = p;
                    s_lane[h] += p;
                }
            } else {
                float v = asv[s] + adn[0];
                v = (v > 0.f) ? v : NEG_SLOPE * v;
                float p = __expf(fminf(v, 60.f));
                sAl[0][lane] = p;
                s_lane[0] += p;
            }
        }
        if (act_g) {
            int k = g;
            bool have = (k < n);
            float pc = 0.f; short8v vc = {};
            if (have) {
                pc = sAl[hc][k];
                vc = *(const short8v*)(H + (long)sSrc[k] * HC + c8);
            }
            while (have) {
                int k1 = k + EPW;
                bool h1 = (k1 < n);
                float p1 = 0.f; short8v v1 = {};
                if (h1) {
                    p1 = sAl[hc][k1];
                    v1 = *(const short8v*)(H + (long)sSrc[k1] * HC + c8);
                }
#pragma unroll
                for (int j = 0; j < 8; ++j)
                    acc[j] += pc * bfu2f((unsigned short)vc[j]);
                k = k1; pc = p1; vc = v1; have = h1;
            }
        }
    }

    // cross-group partial-sum reduce (register butterfly)
    if constexpr (EPW > 1) {
#pragma unroll
        for (int m = TPE; m < 64; m <<= 1)
#pragma unroll
            for (int j = 0; j < 8; ++j) acc[j] += __shfl_xor(acc[j], m);
    }

    // denominator butterfly (all 64 lanes hold the result)
    float den[HH];
#pragma unroll
    for (int h = 0; h < HH; ++h) {
        float sl = s_lane[h];
#pragma unroll
        for (int m = 1; m < 64; m <<= 1) sl += __shfl_xor(sl, m);
        den[h] = sl + 1e-16f;
    }

    if (lane < TPE) {
        float inv = 1.0f / den[hc];
        float4 b0 = *(const float4*)(bias + c8);
        float4 b1 = *(const float4*)(bias + c8 + 4);
        float bb[8] = {b0.x, b0.y, b0.z, b0.w, b1.x, b1.y, b1.z, b1.w};
        short8v o;
#pragma unroll
        for (int j = 0; j < 8; ++j) {
            float r = acc[j] * inv + bb[j];
            if (act == 1) r = fmaxf(r, 0.f);
            else if (act == 2) r = tanhf(r);
            o[j] = (short)__bfloat16_as_ushort(__float2bfloat16(r));
        }
        *(short8v*)(out + (long)d * HC + c8) = o;
    }
}

// ---------------- launch ----------------

extern "C" void kernel_launch(void* const* d_in, const int* in_sizes, int n_in,
                              void* d_out, int out_size, void* d_ws, size_t ws_size,
                              hipStream_t stream) {
    const float* x    = (const float*)d_in[0];
    const int*   ei   = (const int*)d_in[1];
    const float* W1   = (const float*)d_in[2];
    const float* a1s  = (const float*)d_in[3];
    const float* a1d  = (const float*)d_in[4];
    const float* b1   = (const float*)d_in[5];
    const float* W2   = (const float*)d_in[6];
    const float* a2s  = (const float*)d_in[7];
    const float* a2d  = (const float*)d_in[8];
    const float* b2   = (const float*)d_in[9];
    const float* W3   = (const float*)d_in[10];
    const float* a3s  = (const float*)d_in[11];
    const float* a3d  = (const float*)d_in[12];
    const float* b3   = (const float*)d_in[13];
    const float* Wc   = (const float*)d_in[14];
    const float* bc   = (const float*)d_in[15];

    const int F0 = 256;
    int N = in_sizes[0] / F0;          // 50000
    int E = in_sizes[1] / 2;           // 800000
    int Etot = E + N;
    const int* srcI = ei;
    const int* dstI = ei + E;

    // ---- workspace carve ----
    char* p = (char*)d_ws;
    auto alloc = [&](size_t bytes) { void* r = p; p += (bytes + 255) & ~(size_t)255; return r; };
    __hip_bfloat16* xb  = (__hip_bfloat16*)alloc((size_t)N * 256 * 2);
    __hip_bfloat16* Hb  = (__hip_bfloat16*)alloc((size_t)N * 384 * 2);
    __hip_bfloat16* O1  = (__hip_bfloat16*)alloc((size_t)N * 384 * 2);
    __hip_bfloat16* O2  = (__hip_bfloat16*)alloc((size_t)N * 128 * 2);
    __hip_bfloat16* O3  = (__hip_bfloat16*)alloc((size_t)N * 64 * 2);
    __hip_bfloat16* W1T = (__hip_bfloat16*)alloc((size_t)(384 + 8) * 256 * 2);
    __hip_bfloat16* W2T = (__hip_bfloat16*)alloc((size_t)(128 + 2) * 384 * 2);
    __hip_bfloat16* W3T = (__hip_bfloat16*)alloc((size_t)(64 + 2) * 128 * 2);
    __hip_bfloat16* WcT = (__hip_bfloat16*)alloc((size_t)40 * 64 * 2);
    float* as_  = (float*)alloc((size_t)N * 4 * 4);
    float* ad_  = (float*)alloc((size_t)N * 4 * 4);
    int* rowptr = (int*)alloc((size_t)(N + 1) * 4);
    int* cnt    = (int*)alloc((size_t)N * 4);
    int* esrc   = (int*)alloc((size_t)Etot * 4);
    int* bsum   = (int*)alloc(256 * 4);

    // ---- merged prep (x cast + weights + projections + cnt zero) ----
    long nx4 = (long)N * 256 / 4;                 // 3.2M
    long ptot = nx4 + 161280 + N;
    prep_all<<<(int)((ptot + 255) / 256), 256, 0, stream>>>(
        x, xb, nx4, W1, a1s, a1d, W2, a2s, a2d, W3, a3s, a3d, Wc,
        W1T, W2T, W3T, WcT, cnt, N);

    // ---- CSR build ----
    int nb = (N + 255) / 256;
    hist_kernel<<<(Etot + 255) / 256, 256, 0, stream>>>(dstI, cnt, E, Etot);
    scan1<<<nb, 256, 0, stream>>>(cnt, rowptr, bsum, N);
    scan2<<<1, 256, 0, stream>>>(bsum, nb);
    scan3<<<nb, 256, 0, stream>>>(rowptr, bsum, cnt, N, Etot);
    fill_kernel<<<(Etot + 255) / 256, 256, 0, stream>>>(srcI, dstI, rowptr, cnt, esrc, E, Etot);

    auto run_gemm = [&](const __hip_bfloat16* X, int Fin, const __hip_bfloat16* WT,
                        int Hh, int C) {
        int HC = Hh * C;
        int Nlog = HC + 2 * Hh;
        dim3 gg((Nlog + 63) / 64, (N + 127) / 128);
        gemm_bf16<<<gg, 256, 0, stream>>>(X, WT, Hb, nullptr, nullptr, as_, ad_,
                                          N, Fin, Nlog, HC, Hh);
    };
    int gwb = (N + 3) / 4;   // 4 nodes (waves) per block

    // Layer 1: 256 -> 4x96, relu
    run_gemm(xb, 256, W1T, 4, 96);
    gat_gather_wave<4, 96><<<gwb, 256, 0, stream>>>(rowptr, esrc, Hb, as_, ad_, b1, O1, 1, N);
    // Layer 2: 384 -> 1x128, tanh
    run_gemm(O1, 384, W2T, 1, 128);
    gat_gather_wave<1, 128><<<gwb, 256, 0, stream>>>(rowptr, esrc, Hb, as_, ad_, b2, O2, 2, N);
    // Layer 3: 128 -> 1x64, tanh
    run_gemm(O2, 128, W3T, 1, 64);
    gat_gather_wave<1, 64><<<gwb, 256, 0, stream>>>(rowptr, esrc, Hb, as_, ad_, b3, O3, 2, N);

    // Classifier: out = O3 @ Wc + bc   [N,40] f32
    float* out = (float*)d_out;
    dim3 gg((40 + 63) / 64, (N + 127) / 128);
    gemm_bf16<<<gg, 256, 0, stream>>>(O3, WcT, nullptr, out, bc, as_, ad_,
                                      N, 64, 40, 40, 0);
}